// Round 2
// baseline (790.080 us; speedup 1.0000x reference)
//
#include <hip/hip_runtime.h>
#include <hip/hip_bf16.h>

// ---------------------------------------------------------------------------
// RecurrentAttention: B=4, L=1024, D_MODEL=1024, N_HEAD=16, D_HEAD=64
// Inputs/outputs fp32; internals bf16, fp32 accumulate.
//
// ws (bf16-el units, 35.65 MB proven-safe):
//   Wb    [0, 4194304)         weights rotate -> M_xs (x-attn OutB)
//   q1q2  [4194304, 12582912)  kvs_b -> Q outputs [4096x2048] -> Wt_xp
//   Mbuf  [12582912, 16777216) kvx_b -> qs_b -> M_s -> qx_b -> M_x
//   kvpx  [16777216,+524288)   Kp [4096x64] + Vt [4][64][1024]
//   kvps  [17301504,+524288)
// d_out lo = bf16 scratch for M_sx (dead before final x_out write).
// All launches sequential on one stream -> aliasing race-free.
//
// attn v3: structural change ONLY vs the proven 568us baseline.
//   - K/V read directly from global (L2-resident, 256 KB per (b,path));
//     no K/V LDS staging, no __syncthreads at all.
//   - LDS = Ps transpose buffer only (16.9 KB) -> occupancy cap lifted.
//   - Value path IDENTICAL to baseline: __expf, manual f2bf, qscale 0.125.
//     (Round-1's cvt_pk/v_exp inline-asm path caused a 5x-threshold
//      numeric fail; reverted pending isolated A/B.)
// ---------------------------------------------------------------------------

typedef short short8 __attribute__((ext_vector_type(8)));
typedef short short4v __attribute__((ext_vector_type(4)));
typedef float floatx4 __attribute__((ext_vector_type(4)));

__device__ __forceinline__ float b2f(ushort h) {
    union { unsigned u; float f; } v; v.u = ((unsigned)h) << 16; return v.f;
}
__device__ __forceinline__ ushort f2bf(float f) {
    union { float f; unsigned u; } v; v.f = f;
    return (ushort)((v.u + 0x7FFFu + ((v.u >> 16) & 1u)) >> 16);
}
__device__ __forceinline__ void gl_lds16(const ushort* g, ushort* l) {
    __builtin_amdgcn_global_load_lds(
        (const __attribute__((address_space(1))) void*)g,
        (__attribute__((address_space(3))) void*)l, 16, 0, 0);
}

// ---------------------------------------------------------------------------
// Batched fp32 -> bf16 cast. grid (4096, 1, nz), block 256: 4 el/thread.
// ---------------------------------------------------------------------------
struct CB { const float* src[2]; ushort* dst[2]; };

__global__ __launch_bounds__(256) void castb(CB cb) {
    const int z = blockIdx.z;
    const float* s = cb.src[z];
    ushort* d = cb.dst[z];
    const size_t i = ((size_t)blockIdx.x * 256 + threadIdx.x) * 4;
    floatx4 f = *(const floatx4*)&s[i];
    short4v o;
#pragma unroll
    for (int k = 0; k < 4; k++) o[k] = (short)f2bf(f[k]);
    *(short4v*)&d[i] = o;
}

// ---------------------------------------------------------------------------
// Batched fp32->bf16 weight transpose: Wt[n*K+k] = bf16(W[k*N+n])
// ---------------------------------------------------------------------------
struct TB { const float* src[4]; ushort* dst[4]; int K[4]; int N[4]; };

__global__ __launch_bounds__(256) void tbatch(TB tb) {
    __shared__ float tile[32][33];
    const int wi = blockIdx.z;
    const int K = tb.K[wi], N = tb.N[wi];
    const int k0 = blockIdx.x * 32, n0 = blockIdx.y * 32;
    if (k0 >= K || n0 >= N) return;
    const float* W = tb.src[wi];
    ushort* Wt = tb.dst[wi];
    const int tx = threadIdx.x & 31, ty = threadIdx.x >> 5;
#pragma unroll
    for (int i = ty; i < 32; i += 8)
        tile[i][tx] = W[(size_t)(k0 + i) * N + n0 + tx];
    __syncthreads();
#pragma unroll
    for (int i = ty; i < 32; i += 8)
        Wt[(size_t)(n0 + i) * K + k0 + tx] = f2bf(tile[tx][i]);
}

// ---------------------------------------------------------------------------
// Q-GEMM (all bf16, fully async staged): C = cscale*(A[4096x1024] @ Bt^T),
// Bt [2048][1024], C bf16 ldc=2048. grid (32, 16), block 256.
// ---------------------------------------------------------------------------
__global__ __launch_bounds__(256) void gemm_q(
    const ushort* __restrict__ A, const ushort* __restrict__ Bt,
    ushort* __restrict__ C, float cscale)
{
    __shared__ ushort As[128 * 32];
    __shared__ ushort Bs[128 * 32];
    const int t = threadIdx.x;
    const int lane = t & 63, w = t >> 6;
    const int q = lane >> 4, li = lane & 15;
    const int wr = (w >> 1) * 64, wc = (w & 1) * 64;
    const int rowA = blockIdx.x * 128, colB = blockIdx.y * 128;
    const int ar = rowA + w * 32 + (lane >> 2);
    const int br = colB + w * 32 + (lane >> 2);
    const int cl = (lane & 3) * 8;
    ushort* adst = &As[w * 32 * 32];
    ushort* bdst = &Bs[w * 32 * 32];

    floatx4 acc[4][4];
    const floatx4 z4 = {0.f, 0.f, 0.f, 0.f};
#pragma unroll
    for (int i = 0; i < 4; i++)
#pragma unroll
        for (int j = 0; j < 4; j++) acc[i][j] = z4;

    for (int k0 = 0; k0 < 1024; k0 += 32) {
        gl_lds16(A + (size_t)ar * 1024 + k0 + cl, adst);
        gl_lds16(A + (size_t)(ar + 16) * 1024 + k0 + cl, adst + 16 * 32);
        gl_lds16(Bt + (size_t)br * 1024 + k0 + cl, bdst);
        gl_lds16(Bt + (size_t)(br + 16) * 1024 + k0 + cl, bdst + 16 * 32);
        __syncthreads();
        short8 af[4], bf[4];
#pragma unroll
        for (int i = 0; i < 4; i++) af[i] = *(const short8*)&As[(wr + i * 16 + li) * 32 + q * 8];
#pragma unroll
        for (int j = 0; j < 4; j++) bf[j] = *(const short8*)&Bs[(wc + j * 16 + li) * 32 + q * 8];
#pragma unroll
        for (int i = 0; i < 4; i++)
#pragma unroll
            for (int j = 0; j < 4; j++)
                acc[i][j] = __builtin_amdgcn_mfma_f32_16x16x32_bf16(af[i], bf[j], acc[i][j], 0, 0, 0);
        __syncthreads();
    }
#pragma unroll
    for (int i = 0; i < 4; i++) {
        const int rowb = rowA + wr + i * 16 + q * 4;
#pragma unroll
        for (int j = 0; j < 4; j++) {
            const int col = colB + wc + j * 16 + li;
#pragma unroll
            for (int r = 0; r < 4; r++)
                C[(size_t)(rowb + r) * 2048 + col] = f2bf(acc[i][j][r] * cscale);
        }
    }
}

// ---------------------------------------------------------------------------
// KV-GEMM (z=2 batched): C = A[4096x1024] @ Bt[128][1024]^T; epilogue splits
// cols 0-63 -> Kp[row*64+col], 64-127 -> Vt[b][d][tok]. grid (32,1,2).
// ---------------------------------------------------------------------------
__global__ __launch_bounds__(256) void gemm_kv(
    const ushort* __restrict__ A0, const ushort* __restrict__ A1,
    const ushort* __restrict__ B0, const ushort* __restrict__ B1,
    ushort* __restrict__ C0, ushort* __restrict__ C1,
    ushort* __restrict__ vt0, ushort* __restrict__ vt1)
{
    __shared__ ushort As[128 * 32];
    __shared__ ushort Bs[128 * 32];
    const int z = blockIdx.z;
    const ushort* A = z ? A1 : A0;
    const ushort* Bt = z ? B1 : B0;
    ushort* Kp = z ? C1 : C0;
    ushort* vt = z ? vt1 : vt0;

    const int t = threadIdx.x;
    const int lane = t & 63, w = t >> 6;
    const int q = lane >> 4, li = lane & 15;
    const int wr = (w >> 1) * 64, wc = (w & 1) * 64;
    const int rowA = blockIdx.x * 128;
    const int ar = rowA + w * 32 + (lane >> 2);
    const int br = w * 32 + (lane >> 2);
    const int cl = (lane & 3) * 8;
    ushort* adst = &As[w * 32 * 32];
    ushort* bdst = &Bs[w * 32 * 32];

    floatx4 acc[4][4];
    const floatx4 z4 = {0.f, 0.f, 0.f, 0.f};
#pragma unroll
    for (int i = 0; i < 4; i++)
#pragma unroll
        for (int j = 0; j < 4; j++) acc[i][j] = z4;

    for (int k0 = 0; k0 < 1024; k0 += 32) {
        gl_lds16(A + (size_t)ar * 1024 + k0 + cl, adst);
        gl_lds16(A + (size_t)(ar + 16) * 1024 + k0 + cl, adst + 16 * 32);
        gl_lds16(Bt + (size_t)br * 1024 + k0 + cl, bdst);
        gl_lds16(Bt + (size_t)(br + 16) * 1024 + k0 + cl, bdst + 16 * 32);
        __syncthreads();
        short8 af[4], bf[4];
#pragma unroll
        for (int i = 0; i < 4; i++) af[i] = *(const short8*)&As[(wr + i * 16 + li) * 32 + q * 8];
#pragma unroll
        for (int j = 0; j < 4; j++) bf[j] = *(const short8*)&Bs[(wc + j * 16 + li) * 32 + q * 8];
#pragma unroll
        for (int i = 0; i < 4; i++)
#pragma unroll
            for (int j = 0; j < 4; j++)
                acc[i][j] = __builtin_amdgcn_mfma_f32_16x16x32_bf16(af[i], bf[j], acc[i][j], 0, 0, 0);
        __syncthreads();
    }
#pragma unroll
    for (int i = 0; i < 4; i++) {
        const int rowb = rowA + wr + i * 16 + q * 4;
#pragma unroll
        for (int j = 0; j < 4; j++) {
            const int col = wc + j * 16 + li;
#pragma unroll
            for (int r = 0; r < 4; r++) {
                const int row = rowb + r;
                const ushort vb = f2bf(acc[i][j][r]);
                if (col < 64) Kp[(size_t)row * 64 + col] = vb;
                else vt[((row >> 10) << 16) + ((col - 64) << 10) + (row & 1023)] = vb;
            }
        }
    }
}

// ---------------------------------------------------------------------------
// Fused concat-projection GEMM, K=2048: C = [A1|A2] @ Bt^T + bias (fp32 out).
// K-remap ks = (kp>>6)*128 + (kp&63) + 64*(k>=1024). grid (32, 8).
// ---------------------------------------------------------------------------
__global__ __launch_bounds__(256) void gemm_proj(
    const ushort* __restrict__ A1, const ushort* __restrict__ A2,
    const ushort* __restrict__ Bt, const float* __restrict__ bias,
    float* __restrict__ C)
{
    __shared__ ushort As[128 * 32];
    __shared__ ushort Bs[128 * 32];
    const int t = threadIdx.x;
    const int lane = t & 63, w = t >> 6;
    const int q = lane >> 4, li = lane & 15;
    const int wr = (w >> 1) * 64, wc = (w & 1) * 64;
    const int rowA = blockIdx.x * 128, colB = blockIdx.y * 128;
    const int ar = rowA + w * 32 + (lane >> 2);
    const int br = colB + w * 32 + (lane >> 2);
    const int cl = (lane & 3) * 8;
    ushort* adst = &As[w * 32 * 32];
    ushort* bdst = &Bs[w * 32 * 32];

    floatx4 acc[4][4];
    const floatx4 z4 = {0.f, 0.f, 0.f, 0.f};
#pragma unroll
    for (int i = 0; i < 4; i++)
#pragma unroll
        for (int j = 0; j < 4; j++) acc[i][j] = z4;

    for (int k0 = 0; k0 < 2048; k0 += 32) {
        const ushort* Ap = (k0 < 1024) ? A1 : A2;
        const int kc = k0 & 1023;
        const int kp = kc + cl;
        const int ks = ((kp >> 6) << 7) + (kp & 63) + ((k0 >= 1024) ? 64 : 0);
        gl_lds16(Ap + (size_t)ar * 1024 + kc + cl, adst);
        gl_lds16(Ap + (size_t)(ar + 16) * 1024 + kc + cl, adst + 16 * 32);
        gl_lds16(Bt + (size_t)br * 2048 + ks, bdst);
        gl_lds16(Bt + (size_t)(br + 16) * 2048 + ks, bdst + 16 * 32);
        __syncthreads();
        short8 af[4], bf[4];
#pragma unroll
        for (int i = 0; i < 4; i++) af[i] = *(const short8*)&As[(wr + i * 16 + li) * 32 + q * 8];
#pragma unroll
        for (int j = 0; j < 4; j++) bf[j] = *(const short8*)&Bs[(wc + j * 16 + li) * 32 + q * 8];
#pragma unroll
        for (int i = 0; i < 4; i++)
#pragma unroll
            for (int j = 0; j < 4; j++)
                acc[i][j] = __builtin_amdgcn_mfma_f32_16x16x32_bf16(af[i], bf[j], acc[i][j], 0, 0, 0);
        __syncthreads();
    }
#pragma unroll
    for (int i = 0; i < 4; i++) {
        const int rowb = rowA + wr + i * 16 + q * 4;
#pragma unroll
        for (int j = 0; j < 4; j++) {
            const int col = colB + wc + j * 16 + li;
            const float bv = bias[col];
#pragma unroll
            for (int r = 0; r < 4; r++)
                C[(size_t)(rowb + r) * 1024 + col] = acc[i][j][r] + bv;
        }
    }
}

// ---------------------------------------------------------------------------
// Flash attention v3: barrier-free, K/V fragments read directly from global
// (K+V = 256 KB per (b,path) -> L2-resident; staging them in LDS was pure
// overhead + forced 2 barriers/tile + capped occupancy at 3 blk/CU).
// LDS holds only the wave-private Ps transpose buffer (16.9 KB).
// Value path identical to the proven baseline (__expf, f2bf).
// grid (16 qtiles, 16 heads, 8 = b*2+a2), block 256.
// ---------------------------------------------------------------------------
__global__ __launch_bounds__(256, 4) void attn_kernel(
    const ushort* __restrict__ Qbase,
    const ushort* __restrict__ KVa, const ushort* __restrict__ KVb,
    ushort* __restrict__ OutA, ushort* __restrict__ OutB)
{
    __shared__ ushort Ps[64 * 132];  // [qrow][key], wave-private rows

    const int t = threadIdx.x;
    const int lane = t & 63, w = t >> 6;
    const int q = lane >> 4, li = lane & 15;
    const int qt = blockIdx.x, h = blockIdx.y;
    const int z = blockIdx.z, b = z >> 1, a2 = z & 1;

    const ushort* Q  = Qbase + (a2 ? 1024 : 0);
    const ushort* KV = a2 ? KVb : KVa;
    ushort* Out      = a2 ? OutB : OutA;
    // per-lane fragment base pointers (K: [tok][d], V: [b][d][tok]) — same
    // (li, q*8) fragment mapping the old LDS reads used, just global.
    const ushort* Kp = KV + (size_t)(b * 1024 + li) * 64 + q * 8;
    const ushort* Vp = KV + 262144 + (size_t)(b * 64 + li) * 1024 + q * 8;

    const size_t qrow = (size_t)(b * 1024 + qt * 64 + w * 16 + li);
    short8 qf0 = *(const short8*)&Q[qrow * 2048 + h * 64 + q * 8];
    short8 qf1 = *(const short8*)&Q[qrow * 2048 + h * 64 + 32 + q * 8];

    float lsum[4] = {0.f, 0.f, 0.f, 0.f};
    floatx4 O[4];
    const floatx4 z4 = {0.f, 0.f, 0.f, 0.f};
#pragma unroll
    for (int j = 0; j < 4; j++) O[j] = z4;

    const int psw = (w * 16 + q * 4) * 132 + li;  // P write base (row q*4, col li)
    const int psr = (w * 16 + li) * 132 + q * 8;  // P read base  (row li, keys q*8..)

    for (int kt = 0; kt < 8; kt++) {
        const int kof = kt * 128 * 64;   // K element offset: 128 key-rows/tile
        const int vof = kt * 128;        // V element offset: 128 keys along tok
        // --- QK^T + exp, 16 keys per j ---
        floatx4 s4[8];
#pragma unroll
        for (int j = 0; j < 8; j++) {
            short8 kf0 = *(const short8*)&Kp[kof + j * 16 * 64];
            short8 kf1 = *(const short8*)&Kp[kof + j * 16 * 64 + 32];
            s4[j] = __builtin_amdgcn_mfma_f32_16x16x32_bf16(qf0, kf0, z4, 0, 0, 0);
            s4[j] = __builtin_amdgcn_mfma_f32_16x16x32_bf16(qf1, kf1, s4[j], 0, 0, 0);
        }
#pragma unroll
        for (int j = 0; j < 8; j++)
#pragma unroll
            for (int r = 0; r < 4; r++)
                s4[j][r] = __expf(s4[j][r]);
#pragma unroll
        for (int r = 0; r < 4; r++) {
            float a = (s4[0][r] + s4[1][r]) + (s4[2][r] + s4[3][r]);
            float c = (s4[4][r] + s4[5][r]) + (s4[6][r] + s4[7][r]);
            lsum[r] += a + c;
        }
#pragma unroll
        for (int j = 0; j < 8; j++)
#pragma unroll
            for (int r = 0; r < 4; r++)
                Ps[psw + r * 132 + j * 16] = f2bf(s4[j][r]);
        // no barrier: Ps rows are wave-private; in-wave LDS ops are in-order
        // --- PV, V fragments straight from global (L2) ---
#pragma unroll
        for (int kk = 0; kk < 4; kk++) {
            short8 pf = *(const short8*)&Ps[psr + kk * 32];
#pragma unroll
            for (int jn = 0; jn < 4; jn++) {
                short8 vf = *(const short8*)&Vp[(size_t)(jn * 16) * 1024 + vof + kk * 32];
                O[jn] = __builtin_amdgcn_mfma_f32_16x16x32_bf16(pf, vf, O[jn], 0, 0, 0);
            }
        }
    }

#pragma unroll
    for (int off = 1; off < 16; off <<= 1)
#pragma unroll
        for (int r = 0; r < 4; r++)
            lsum[r] += __shfl_xor(lsum[r], off);

    const int orow = b * 1024 + qt * 64 + w * 16 + q * 4;
#pragma unroll
    for (int r = 0; r < 4; r++) {
        const float inv = 1.f / lsum[r];
#pragma unroll
        for (int j = 0; j < 4; j++)
            Out[(size_t)(orow + r) * 1024 + h * 64 + j * 16 + li] = f2bf(O[j][r] * inv);
    }
}

// ---------------------------------------------------------------------------
extern "C" void kernel_launch(void* const* d_in, const int* in_sizes, int n_in,
                              void* d_out, int out_size, void* d_ws, size_t ws_size,
                              hipStream_t stream) {
    const float* qx    = (const float*)d_in[0];
    const float* kvx   = (const float*)d_in[1];
    const float* qs    = (const float*)d_in[2];
    const float* kvs   = (const float*)d_in[3];
    const float* w_qx1 = (const float*)d_in[4];
    const float* w_qs1 = (const float*)d_in[5];
    const float* w_qx2 = (const float*)d_in[6];
    const float* w_qs2 = (const float*)d_in[7];
    const float* w_kvx = (const float*)d_in[8];
    const float* w_kvs = (const float*)d_in[9];
    const float* w_xp  = (const float*)d_in[10];
    const float* b_xp  = (const float*)d_in[11];
    const float* w_sp  = (const float*)d_in[12];
    const float* b_sp  = (const float*)d_in[13];
    float* out = (float*)d_out;
    (void)ws_size; (void)in_sizes; (void)n_in; (void)out_size;

    ushort* ws   = (ushort*)d_ws;
    ushort* Wb   = ws;
    ushort* q1q2 = ws + 4194304;
    ushort* Mbuf = ws + 12582912;
    ushort* kvpx = ws + 16777216;
    ushort* kvps = ws + 17301504;

    // 1) cast kv activations: kvx_b -> Mbuf, kvs_b -> q1q2 (both dead regions)
    CB c1; c1.src[0] = kvx; c1.dst[0] = Mbuf; c1.src[1] = kvs; c1.dst[1] = q1q2;
    castb<<<dim3(4096, 1, 2), 256, 0, stream>>>(c1);

    // 2) transpose kv + s-path Q weights into Wb
    TB tb1;
    tb1.src[0] = w_kvx; tb1.dst[0] = Wb;           tb1.K[0] = 1024; tb1.N[0] = 128;
    tb1.src[1] = w_kvs; tb1.dst[1] = Wb + 131072;  tb1.K[1] = 1024; tb1.N[1] = 128;
    tb1.src[2] = w_qs1; tb1.dst[2] = Wb + 262144;  tb1.K[2] = 1024; tb1.N[2] = 1024;
    tb1.src[3] = w_qs2; tb1.dst[3] = Wb + 1310720; tb1.K[3] = 1024; tb1.N[3] = 1024;
    tbatch<<<dim3(32, 32, 4), 256, 0, stream>>>(tb1);

    // 3) kv projections (z=2): K->Kp, V->Vt
    gemm_kv<<<dim3(32, 1, 2), 256, 0, stream>>>(
        Mbuf, q1q2, Wb, Wb + 131072, kvpx, kvps, kvpx + 262144, kvps + 262144);

    // 4) cast qs -> Mbuf (kvx_b dead)
    CB c2; c2.src[0] = qs; c2.dst[0] = Mbuf; c2.src[1] = qs; c2.dst[1] = Mbuf;
    castb<<<dim3(4096, 1, 1), 256, 0, stream>>>(c2);

    // 5) s-path Q GEMM: q1s|q2s -> q1q2 (kvs_b dead), scale 1/8 folded
    gemm_q<<<dim3(32, 16), 256, 0, stream>>>(Mbuf, Wb + 262144, q1q2, 0.125f);

    // 6) s attention: M_s -> Mbuf (qs_b dead), M_sx -> d_out lo (bf16 scratch)
    attn_kernel<<<dim3(16, 16, 8), 256, 0, stream>>>(q1q2, kvps, kvpx, Mbuf, (ushort*)out);

    // 7) transpose sp + x-path Q weights (Wt_kv/Wt_qs dead)
    TB tb2;
    tb2.src[0] = w_sp;  tb2.dst[0] = Wb;           tb2.K[0] = 2048; tb2.N[0] = 1024;
    tb2.src[1] = w_qx1; tb2.dst[1] = Wb + 2097152; tb2.K[1] = 1024; tb2.N[1] = 1024;
    tb2.src[2] = w_qx2; tb2.dst[2] = Wb + 3145728; tb2.K[2] = 1024; tb2.N[2] = 1024;
    tb2.src[3] = w_sp;  tb2.dst[3] = Wb;           tb2.K[3] = 0;    tb2.N[3] = 0;
    tbatch<<<dim3(64, 32, 3), 256, 0, stream>>>(tb2);

    // 8) s_out = [M_sx | M_s] @ Wsp^T + b_sp -> d_out hi (fp32)
    gemm_proj<<<dim3(32, 8), 256, 0, stream>>>((ushort*)out, Mbuf, Wb, b_sp, out + 4194304);

    // 9) cast qx -> Mbuf (M_s dead)
    CB c3; c3.src[0] = qx; c3.dst[0] = Mbuf; c3.src[1] = qx; c3.dst[1] = Mbuf;
    castb<<<dim3(4096, 1, 1), 256, 0, stream>>>(c3);

    // 10) x-path Q GEMM -> q1q2 (dead after s-attn)
    gemm_q<<<dim3(32, 16), 256, 0, stream>>>(Mbuf, Wb + 2097152, q1q2, 0.125f);

    // 11) x attention: M_x -> Mbuf (qx_b dead), M_xs -> Wb (weights dead)
    attn_kernel<<<dim3(16, 16, 8), 256, 0, stream>>>(q1q2, kvpx, kvps, Mbuf, Wb);

    // 12) transpose xp -> q1q2 (dead after x-attn)
    TB tb3;
    tb3.src[0] = w_xp; tb3.dst[0] = q1q2; tb3.K[0] = 2048; tb3.N[0] = 1024;
    tb3.src[1] = w_xp; tb3.dst[1] = q1q2; tb3.K[1] = 0;    tb3.N[1] = 0;
    tb3.src[2] = w_xp; tb3.dst[2] = q1q2; tb3.K[2] = 0;    tb3.N[2] = 0;
    tb3.src[3] = w_xp; tb3.dst[3] = q1q2; tb3.K[3] = 0;    tb3.N[3] = 0;
    tbatch<<<dim3(64, 32, 1), 256, 0, stream>>>(tb3);

    // 13) x_out = [M_xs | M_x] @ Wxp^T + b_xp -> d_out lo (M_sx scratch dead)
    gemm_proj<<<dim3(32, 8), 256, 0, stream>>>(Wb, Mbuf, q1q2, b_xp, out);
}

// Round 3
// 560.976 us; speedup vs baseline: 1.4084x; 1.4084x over previous
//
#include <hip/hip_runtime.h>
#include <hip/hip_bf16.h>

// ---------------------------------------------------------------------------
// RecurrentAttention: B=4, L=1024, D_MODEL=1024, N_HEAD=16, D_HEAD=64
// Inputs/outputs fp32; internals bf16, fp32 accumulate.
//
// ws (bf16-el units, 35.65 MB proven-safe):
//   Wb    [0, 4194304)         weights rotate -> M_xs (x-attn OutB)
//   q1q2  [4194304, 12582912)  kvs_b -> Q outputs [4096x2048] -> Wt_xp
//   Mbuf  [12582912, 16777216) kvx_b -> qs_b -> M_s -> qx_b -> M_x
//   kvpx  [16777216,+524288)   Kp [4096x64] + Vt [4][64][1024]
//   kvps  [17301504,+524288)
// d_out lo = bf16 scratch for M_sx (dead before final x_out write).
// All launches sequential on one stream -> aliasing race-free.
//
// attn v4 = round-0 proven structure (LDS-staged K/V, Ps round-trip,
// __expf/f2bf value path) + T14 async-STAGE split: tile kt+1's global
// loads issue into REGISTERS right after the staging barrier, so L2
// latency hides under the current tile's QK/softmax/PV; regs drain to
// LDS at the top of the next iteration. + s_setprio(1) around MFMA
// clusters (m191). Round-2 lesson: direct-global MFMA operands are
// latency-bound (L1 thrash, 240us); staging is latency amortization.
// ---------------------------------------------------------------------------

typedef short short8 __attribute__((ext_vector_type(8)));
typedef short short4v __attribute__((ext_vector_type(4)));
typedef float floatx4 __attribute__((ext_vector_type(4)));

__device__ __forceinline__ float b2f(ushort h) {
    union { unsigned u; float f; } v; v.u = ((unsigned)h) << 16; return v.f;
}
__device__ __forceinline__ ushort f2bf(float f) {
    union { float f; unsigned u; } v; v.f = f;
    return (ushort)((v.u + 0x7FFFu + ((v.u >> 16) & 1u)) >> 16);
}
__device__ __forceinline__ void gl_lds16(const ushort* g, ushort* l) {
    __builtin_amdgcn_global_load_lds(
        (const __attribute__((address_space(1))) void*)g,
        (__attribute__((address_space(3))) void*)l, 16, 0, 0);
}

// ---------------------------------------------------------------------------
// Batched fp32 -> bf16 cast. grid (4096, 1, nz), block 256: 4 el/thread.
// ---------------------------------------------------------------------------
struct CB { const float* src[2]; ushort* dst[2]; };

__global__ __launch_bounds__(256) void castb(CB cb) {
    const int z = blockIdx.z;
    const float* s = cb.src[z];
    ushort* d = cb.dst[z];
    const size_t i = ((size_t)blockIdx.x * 256 + threadIdx.x) * 4;
    floatx4 f = *(const floatx4*)&s[i];
    short4v o;
#pragma unroll
    for (int k = 0; k < 4; k++) o[k] = (short)f2bf(f[k]);
    *(short4v*)&d[i] = o;
}

// ---------------------------------------------------------------------------
// Batched fp32->bf16 weight transpose: Wt[n*K+k] = bf16(W[k*N+n])
// ---------------------------------------------------------------------------
struct TB { const float* src[4]; ushort* dst[4]; int K[4]; int N[4]; };

__global__ __launch_bounds__(256) void tbatch(TB tb) {
    __shared__ float tile[32][33];
    const int wi = blockIdx.z;
    const int K = tb.K[wi], N = tb.N[wi];
    const int k0 = blockIdx.x * 32, n0 = blockIdx.y * 32;
    if (k0 >= K || n0 >= N) return;
    const float* W = tb.src[wi];
    ushort* Wt = tb.dst[wi];
    const int tx = threadIdx.x & 31, ty = threadIdx.x >> 5;
#pragma unroll
    for (int i = ty; i < 32; i += 8)
        tile[i][tx] = W[(size_t)(k0 + i) * N + n0 + tx];
    __syncthreads();
#pragma unroll
    for (int i = ty; i < 32; i += 8)
        Wt[(size_t)(n0 + i) * K + k0 + tx] = f2bf(tile[tx][i]);
}

// ---------------------------------------------------------------------------
// Q-GEMM (all bf16, fully async staged): C = cscale*(A[4096x1024] @ Bt^T),
// Bt [2048][1024], C bf16 ldc=2048. grid (32, 16), block 256.
// ---------------------------------------------------------------------------
__global__ __launch_bounds__(256) void gemm_q(
    const ushort* __restrict__ A, const ushort* __restrict__ Bt,
    ushort* __restrict__ C, float cscale)
{
    __shared__ ushort As[128 * 32];
    __shared__ ushort Bs[128 * 32];
    const int t = threadIdx.x;
    const int lane = t & 63, w = t >> 6;
    const int q = lane >> 4, li = lane & 15;
    const int wr = (w >> 1) * 64, wc = (w & 1) * 64;
    const int rowA = blockIdx.x * 128, colB = blockIdx.y * 128;
    const int ar = rowA + w * 32 + (lane >> 2);
    const int br = colB + w * 32 + (lane >> 2);
    const int cl = (lane & 3) * 8;
    ushort* adst = &As[w * 32 * 32];
    ushort* bdst = &Bs[w * 32 * 32];

    floatx4 acc[4][4];
    const floatx4 z4 = {0.f, 0.f, 0.f, 0.f};
#pragma unroll
    for (int i = 0; i < 4; i++)
#pragma unroll
        for (int j = 0; j < 4; j++) acc[i][j] = z4;

    for (int k0 = 0; k0 < 1024; k0 += 32) {
        gl_lds16(A + (size_t)ar * 1024 + k0 + cl, adst);
        gl_lds16(A + (size_t)(ar + 16) * 1024 + k0 + cl, adst + 16 * 32);
        gl_lds16(Bt + (size_t)br * 1024 + k0 + cl, bdst);
        gl_lds16(Bt + (size_t)(br + 16) * 1024 + k0 + cl, bdst + 16 * 32);
        __syncthreads();
        short8 af[4], bf[4];
#pragma unroll
        for (int i = 0; i < 4; i++) af[i] = *(const short8*)&As[(wr + i * 16 + li) * 32 + q * 8];
#pragma unroll
        for (int j = 0; j < 4; j++) bf[j] = *(const short8*)&Bs[(wc + j * 16 + li) * 32 + q * 8];
#pragma unroll
        for (int i = 0; i < 4; i++)
#pragma unroll
            for (int j = 0; j < 4; j++)
                acc[i][j] = __builtin_amdgcn_mfma_f32_16x16x32_bf16(af[i], bf[j], acc[i][j], 0, 0, 0);
        __syncthreads();
    }
#pragma unroll
    for (int i = 0; i < 4; i++) {
        const int rowb = rowA + wr + i * 16 + q * 4;
#pragma unroll
        for (int j = 0; j < 4; j++) {
            const int col = colB + wc + j * 16 + li;
#pragma unroll
            for (int r = 0; r < 4; r++)
                C[(size_t)(rowb + r) * 2048 + col] = f2bf(acc[i][j][r] * cscale);
        }
    }
}

// ---------------------------------------------------------------------------
// KV-GEMM (z=2 batched): C = A[4096x1024] @ Bt[128][1024]^T; epilogue splits
// cols 0-63 -> Kp[row*64+col], 64-127 -> Vt[b][d][tok]. grid (32,1,2).
// ---------------------------------------------------------------------------
__global__ __launch_bounds__(256) void gemm_kv(
    const ushort* __restrict__ A0, const ushort* __restrict__ A1,
    const ushort* __restrict__ B0, const ushort* __restrict__ B1,
    ushort* __restrict__ C0, ushort* __restrict__ C1,
    ushort* __restrict__ vt0, ushort* __restrict__ vt1)
{
    __shared__ ushort As[128 * 32];
    __shared__ ushort Bs[128 * 32];
    const int z = blockIdx.z;
    const ushort* A = z ? A1 : A0;
    const ushort* Bt = z ? B1 : B0;
    ushort* Kp = z ? C1 : C0;
    ushort* vt = z ? vt1 : vt0;

    const int t = threadIdx.x;
    const int lane = t & 63, w = t >> 6;
    const int q = lane >> 4, li = lane & 15;
    const int wr = (w >> 1) * 64, wc = (w & 1) * 64;
    const int rowA = blockIdx.x * 128;
    const int ar = rowA + w * 32 + (lane >> 2);
    const int br = w * 32 + (lane >> 2);
    const int cl = (lane & 3) * 8;
    ushort* adst = &As[w * 32 * 32];
    ushort* bdst = &Bs[w * 32 * 32];

    floatx4 acc[4][4];
    const floatx4 z4 = {0.f, 0.f, 0.f, 0.f};
#pragma unroll
    for (int i = 0; i < 4; i++)
#pragma unroll
        for (int j = 0; j < 4; j++) acc[i][j] = z4;

    for (int k0 = 0; k0 < 1024; k0 += 32) {
        gl_lds16(A + (size_t)ar * 1024 + k0 + cl, adst);
        gl_lds16(A + (size_t)(ar + 16) * 1024 + k0 + cl, adst + 16 * 32);
        gl_lds16(Bt + (size_t)br * 1024 + k0 + cl, bdst);
        gl_lds16(Bt + (size_t)(br + 16) * 1024 + k0 + cl, bdst + 16 * 32);
        __syncthreads();
        short8 af[4], bf[4];
#pragma unroll
        for (int i = 0; i < 4; i++) af[i] = *(const short8*)&As[(wr + i * 16 + li) * 32 + q * 8];
#pragma unroll
        for (int j = 0; j < 4; j++) bf[j] = *(const short8*)&Bs[(wc + j * 16 + li) * 32 + q * 8];
#pragma unroll
        for (int i = 0; i < 4; i++)
#pragma unroll
            for (int j = 0; j < 4; j++)
                acc[i][j] = __builtin_amdgcn_mfma_f32_16x16x32_bf16(af[i], bf[j], acc[i][j], 0, 0, 0);
        __syncthreads();
    }
#pragma unroll
    for (int i = 0; i < 4; i++) {
        const int rowb = rowA + wr + i * 16 + q * 4;
#pragma unroll
        for (int j = 0; j < 4; j++) {
            const int col = wc + j * 16 + li;
#pragma unroll
            for (int r = 0; r < 4; r++) {
                const int row = rowb + r;
                const ushort vb = f2bf(acc[i][j][r]);
                if (col < 64) Kp[(size_t)row * 64 + col] = vb;
                else vt[((row >> 10) << 16) + ((col - 64) << 10) + (row & 1023)] = vb;
            }
        }
    }
}

// ---------------------------------------------------------------------------
// Fused concat-projection GEMM, K=2048: C = [A1|A2] @ Bt^T + bias (fp32 out).
// K-remap ks = (kp>>6)*128 + (kp&63) + 64*(k>=1024). grid (32, 8).
// ---------------------------------------------------------------------------
__global__ __launch_bounds__(256) void gemm_proj(
    const ushort* __restrict__ A1, const ushort* __restrict__ A2,
    const ushort* __restrict__ Bt, const float* __restrict__ bias,
    float* __restrict__ C)
{
    __shared__ ushort As[128 * 32];
    __shared__ ushort Bs[128 * 32];
    const int t = threadIdx.x;
    const int lane = t & 63, w = t >> 6;
    const int q = lane >> 4, li = lane & 15;
    const int wr = (w >> 1) * 64, wc = (w & 1) * 64;
    const int rowA = blockIdx.x * 128, colB = blockIdx.y * 128;
    const int ar = rowA + w * 32 + (lane >> 2);
    const int br = colB + w * 32 + (lane >> 2);
    const int cl = (lane & 3) * 8;
    ushort* adst = &As[w * 32 * 32];
    ushort* bdst = &Bs[w * 32 * 32];

    floatx4 acc[4][4];
    const floatx4 z4 = {0.f, 0.f, 0.f, 0.f};
#pragma unroll
    for (int i = 0; i < 4; i++)
#pragma unroll
        for (int j = 0; j < 4; j++) acc[i][j] = z4;

    for (int k0 = 0; k0 < 2048; k0 += 32) {
        const ushort* Ap = (k0 < 1024) ? A1 : A2;
        const int kc = k0 & 1023;
        const int kp = kc + cl;
        const int ks = ((kp >> 6) << 7) + (kp & 63) + ((k0 >= 1024) ? 64 : 0);
        gl_lds16(Ap + (size_t)ar * 1024 + kc + cl, adst);
        gl_lds16(Ap + (size_t)(ar + 16) * 1024 + kc + cl, adst + 16 * 32);
        gl_lds16(Bt + (size_t)br * 2048 + ks, bdst);
        gl_lds16(Bt + (size_t)(br + 16) * 2048 + ks, bdst + 16 * 32);
        __syncthreads();
        short8 af[4], bf[4];
#pragma unroll
        for (int i = 0; i < 4; i++) af[i] = *(const short8*)&As[(wr + i * 16 + li) * 32 + q * 8];
#pragma unroll
        for (int j = 0; j < 4; j++) bf[j] = *(const short8*)&Bs[(wc + j * 16 + li) * 32 + q * 8];
#pragma unroll
        for (int i = 0; i < 4; i++)
#pragma unroll
            for (int j = 0; j < 4; j++)
                acc[i][j] = __builtin_amdgcn_mfma_f32_16x16x32_bf16(af[i], bf[j], acc[i][j], 0, 0, 0);
        __syncthreads();
    }
#pragma unroll
    for (int i = 0; i < 4; i++) {
        const int rowb = rowA + wr + i * 16 + q * 4;
#pragma unroll
        for (int j = 0; j < 4; j++) {
            const int col = colB + wc + j * 16 + li;
            const float bv = bias[col];
#pragma unroll
            for (int r = 0; r < 4; r++)
                C[(size_t)(rowb + r) * 1024 + col] = acc[i][j][r] + bv;
        }
    }
}

// ---------------------------------------------------------------------------
// Flash attention v4: round-0 LDS-staged structure + T14 async-STAGE split.
// Per 128-key tile: drain regs->LDS, barrier, ISSUE next tile's global
// loads into regs (latency hides under compute), QK/softmax/PV, barrier.
// Ps round-trip is wave-private (no barrier needed). setprio(1) around
// MFMA clusters. grid (16 qtiles, 16 heads, 8 = b*2+a2), block 256.
// 50 KB LDS -> 3 blk/CU (LDS-capped; staging regs are free occupancy-wise).
// ---------------------------------------------------------------------------
__global__ __launch_bounds__(256) void attn_kernel(
    const ushort* __restrict__ Qbase,
    const ushort* __restrict__ KVa, const ushort* __restrict__ KVb,
    ushort* __restrict__ OutA, ushort* __restrict__ OutB)
{
    __shared__ ushort Kt[128 * 68];  // [key][d]    (stride 68: ~2-way)
    __shared__ ushort Vt[64 * 132];  // [d][key]    (stride 132: ~2-way)
    __shared__ ushort Ps[64 * 132];  // [qrow][key] wave-private rows

    const int t = threadIdx.x;
    const int lane = t & 63, w = t >> 6;
    const int q = lane >> 4, li = lane & 15;
    const int qt = blockIdx.x, h = blockIdx.y;
    const int z = blockIdx.z, b = z >> 1, a2 = z & 1;

    const ushort* Q  = Qbase + (a2 ? 1024 : 0);
    const ushort* KV = a2 ? KVb : KVa;
    ushort* Out      = a2 ? OutB : OutA;
    const ushort* Kp = KV;
    const ushort* Vg = KV + 262144;

    const size_t qrow = (size_t)(b * 1024 + qt * 64 + w * 16 + li);
    short8 qf0 = *(const short8*)&Q[qrow * 2048 + h * 64 + q * 8];
    short8 qf1 = *(const short8*)&Q[qrow * 2048 + h * 64 + 32 + q * 8];

    float lsum[4] = {0.f, 0.f, 0.f, 0.f};
    floatx4 O[4];
    const floatx4 z4 = {0.f, 0.f, 0.f, 0.f};
#pragma unroll
    for (int j = 0; j < 4; j++) O[j] = z4;

    const int krow = t >> 1, kch = (t & 1) * 32;  // K: 128 rows x 2 halves
    const int vd = t >> 2, vch = (t & 3) * 32;    // V: 64 d x 4 chunks
    const ushort* ksrc0 = &Kp[(size_t)(b * 1024 + krow) * 64 + kch];
    const ushort* vsrc0 = &Vg[(size_t)(b * 64 + vd) * 1024 + vch];
    ushort* kdst = &Kt[krow * 68 + kch];
    ushort* vdst = &Vt[vd * 132 + vch];

    // T14 prologue: tile 0 -> regs
    short8 kreg[4], vreg[4];
#pragma unroll
    for (int i = 0; i < 4; i++) {
        kreg[i] = *(const short8*)&ksrc0[i * 8];
        vreg[i] = *(const short8*)&vsrc0[i * 8];
    }

    for (int kt = 0; kt < 8; kt++) {
        // drain staged regs -> LDS (vmcnt wait inserted by compiler)
#pragma unroll
        for (int i = 0; i < 4; i++) {
            *(short8*)&kdst[i * 8] = kreg[i];
            *(short8*)&vdst[i * 8] = vreg[i];
        }
        __syncthreads();

        // issue NEXT tile's loads now; latency hides under compute below
        if (kt < 7) {
            const ushort* ksrc = ksrc0 + (size_t)(kt + 1) * 128 * 64;
            const ushort* vsrc = vsrc0 + (kt + 1) * 128;
#pragma unroll
            for (int i = 0; i < 4; i++) {
                kreg[i] = *(const short8*)&ksrc[i * 8];
                vreg[i] = *(const short8*)&vsrc[i * 8];
            }
        }

        floatx4 s4[8];
        __builtin_amdgcn_s_setprio(1);
#pragma unroll
        for (int j = 0; j < 8; j++) {
            short8 kf0 = *(const short8*)&Kt[(j * 16 + li) * 68 + q * 8];
            short8 kf1 = *(const short8*)&Kt[(j * 16 + li) * 68 + 32 + q * 8];
            s4[j] = __builtin_amdgcn_mfma_f32_16x16x32_bf16(qf0, kf0, z4, 0, 0, 0);
            s4[j] = __builtin_amdgcn_mfma_f32_16x16x32_bf16(qf1, kf1, s4[j], 0, 0, 0);
        }
        __builtin_amdgcn_s_setprio(0);
#pragma unroll
        for (int j = 0; j < 8; j++)
#pragma unroll
            for (int r = 0; r < 4; r++)
                s4[j][r] = __expf(s4[j][r]);
#pragma unroll
        for (int r = 0; r < 4; r++) {
            float a = (s4[0][r] + s4[1][r]) + (s4[2][r] + s4[3][r]);
            float c = (s4[4][r] + s4[5][r]) + (s4[6][r] + s4[7][r]);
            lsum[r] += a + c;
        }
#pragma unroll
        for (int j = 0; j < 8; j++)
#pragma unroll
            for (int r = 0; r < 4; r++)
                Ps[(w * 16 + q * 4 + r) * 132 + j * 16 + li] = f2bf(s4[j][r]);
        // no barrier: Ps rows are wave-private; compiler orders via lgkmcnt
        __builtin_amdgcn_s_setprio(1);
#pragma unroll
        for (int kk = 0; kk < 4; kk++) {
            short8 pf = *(const short8*)&Ps[(w * 16 + li) * 132 + kk * 32 + q * 8];
#pragma unroll
            for (int jn = 0; jn < 4; jn++) {
                short8 vf = *(const short8*)&Vt[(jn * 16 + li) * 132 + kk * 32 + q * 8];
                O[jn] = __builtin_amdgcn_mfma_f32_16x16x32_bf16(pf, vf, O[jn], 0, 0, 0);
            }
        }
        __builtin_amdgcn_s_setprio(0);
        __syncthreads();  // retire Kt/Vt readers before next drain
    }

#pragma unroll
    for (int off = 1; off < 16; off <<= 1)
#pragma unroll
        for (int r = 0; r < 4; r++)
            lsum[r] += __shfl_xor(lsum[r], off);

    const int orow = b * 1024 + qt * 64 + w * 16 + q * 4;
#pragma unroll
    for (int r = 0; r < 4; r++) {
        const float inv = 1.f / lsum[r];
#pragma unroll
        for (int j = 0; j < 4; j++)
            Out[(size_t)(orow + r) * 1024 + h * 64 + j * 16 + li] = f2bf(O[j][r] * inv);
    }
}

// ---------------------------------------------------------------------------
extern "C" void kernel_launch(void* const* d_in, const int* in_sizes, int n_in,
                              void* d_out, int out_size, void* d_ws, size_t ws_size,
                              hipStream_t stream) {
    const float* qx    = (const float*)d_in[0];
    const float* kvx   = (const float*)d_in[1];
    const float* qs    = (const float*)d_in[2];
    const float* kvs   = (const float*)d_in[3];
    const float* w_qx1 = (const float*)d_in[4];
    const float* w_qs1 = (const float*)d_in[5];
    const float* w_qx2 = (const float*)d_in[6];
    const float* w_qs2 = (const float*)d_in[7];
    const float* w_kvx = (const float*)d_in[8];
    const float* w_kvs = (const float*)d_in[9];
    const float* w_xp  = (const float*)d_in[10];
    const float* b_xp  = (const float*)d_in[11];
    const float* w_sp  = (const float*)d_in[12];
    const float* b_sp  = (const float*)d_in[13];
    float* out = (float*)d_out;
    (void)ws_size; (void)in_sizes; (void)n_in; (void)out_size;

    ushort* ws   = (ushort*)d_ws;
    ushort* Wb   = ws;
    ushort* q1q2 = ws + 4194304;
    ushort* Mbuf = ws + 12582912;
    ushort* kvpx = ws + 16777216;
    ushort* kvps = ws + 17301504;

    // 1) cast kv activations: kvx_b -> Mbuf, kvs_b -> q1q2 (both dead regions)
    CB c1; c1.src[0] = kvx; c1.dst[0] = Mbuf; c1.src[1] = kvs; c1.dst[1] = q1q2;
    castb<<<dim3(4096, 1, 2), 256, 0, stream>>>(c1);

    // 2) transpose kv + s-path Q weights into Wb
    TB tb1;
    tb1.src[0] = w_kvx; tb1.dst[0] = Wb;           tb1.K[0] = 1024; tb1.N[0] = 128;
    tb1.src[1] = w_kvs; tb1.dst[1] = Wb + 131072;  tb1.K[1] = 1024; tb1.N[1] = 128;
    tb1.src[2] = w_qs1; tb1.dst[2] = Wb + 262144;  tb1.K[2] = 1024; tb1.N[2] = 1024;
    tb1.src[3] = w_qs2; tb1.dst[3] = Wb + 1310720; tb1.K[3] = 1024; tb1.N[3] = 1024;
    tbatch<<<dim3(32, 32, 4), 256, 0, stream>>>(tb1);

    // 3) kv projections (z=2): K->Kp, V->Vt
    gemm_kv<<<dim3(32, 1, 2), 256, 0, stream>>>(
        Mbuf, q1q2, Wb, Wb + 131072, kvpx, kvps, kvpx + 262144, kvps + 262144);

    // 4) cast qs -> Mbuf (kvx_b dead)
    CB c2; c2.src[0] = qs; c2.dst[0] = Mbuf; c2.src[1] = qs; c2.dst[1] = Mbuf;
    castb<<<dim3(4096, 1, 1), 256, 0, stream>>>(c2);

    // 5) s-path Q GEMM: q1s|q2s -> q1q2 (kvs_b dead), scale 1/8 folded
    gemm_q<<<dim3(32, 16), 256, 0, stream>>>(Mbuf, Wb + 262144, q1q2, 0.125f);

    // 6) s attention: M_s -> Mbuf (qs_b dead), M_sx -> d_out lo (bf16 scratch)
    attn_kernel<<<dim3(16, 16, 8), 256, 0, stream>>>(q1q2, kvps, kvpx, Mbuf, (ushort*)out);

    // 7) transpose sp + x-path Q weights (Wt_kv/Wt_qs dead)
    TB tb2;
    tb2.src[0] = w_sp;  tb2.dst[0] = Wb;           tb2.K[0] = 2048; tb2.N[0] = 1024;
    tb2.src[1] = w_qx1; tb2.dst[1] = Wb + 2097152; tb2.K[1] = 1024; tb2.N[1] = 1024;
    tb2.src[2] = w_qx2; tb2.dst[2] = Wb + 3145728; tb2.K[2] = 1024; tb2.N[2] = 1024;
    tb2.src[3] = w_sp;  tb2.dst[3] = Wb;           tb2.K[3] = 0;    tb2.N[3] = 0;
    tbatch<<<dim3(64, 32, 3), 256, 0, stream>>>(tb2);

    // 8) s_out = [M_sx | M_s] @ Wsp^T + b_sp -> d_out hi (fp32)
    gemm_proj<<<dim3(32, 8), 256, 0, stream>>>((ushort*)out, Mbuf, Wb, b_sp, out + 4194304);

    // 9) cast qx -> Mbuf (M_s dead)
    CB c3; c3.src[0] = qx; c3.dst[0] = Mbuf; c3.src[1] = qx; c3.dst[1] = Mbuf;
    castb<<<dim3(4096, 1, 1), 256, 0, stream>>>(c3);

    // 10) x-path Q GEMM -> q1q2 (dead after s-attn)
    gemm_q<<<dim3(32, 16), 256, 0, stream>>>(Mbuf, Wb + 2097152, q1q2, 0.125f);

    // 11) x attention: M_x -> Mbuf (qx_b dead), M_xs -> Wb (weights dead)
    attn_kernel<<<dim3(16, 16, 8), 256, 0, stream>>>(q1q2, kvpx, kvps, Mbuf, Wb);

    // 12) transpose xp -> q1q2 (dead after x-attn)
    TB tb3;
    tb3.src[0] = w_xp; tb3.dst[0] = q1q2; tb3.K[0] = 2048; tb3.N[0] = 1024;
    tb3.src[1] = w_xp; tb3.dst[1] = q1q2; tb3.K[1] = 0;    tb3.N[1] = 0;
    tb3.src[2] = w_xp; tb3.dst[2] = q1q2; tb3.K[2] = 0;    tb3.N[2] = 0;
    tb3.src[3] = w_xp; tb3.dst[3] = q1q2; tb3.K[3] = 0;    tb3.N[3] = 0;
    tbatch<<<dim3(64, 32, 1), 256, 0, stream>>>(tb3);

    // 13) x_out = [M_xs | M_x] @ Wxp^T + b_xp -> d_out lo (M_sx scratch dead)
    gemm_proj<<<dim3(32, 8), 256, 0, stream>>>(Wb, Mbuf, q1q2, b_xp, out);
}

// Round 4
// 558.521 us; speedup vs baseline: 1.4146x; 1.0044x over previous
//
#include <hip/hip_runtime.h>
#include <hip/hip_bf16.h>

// ---------------------------------------------------------------------------
// RecurrentAttention: B=4, L=1024, D_MODEL=1024, N_HEAD=16, D_HEAD=64
// Inputs/outputs fp32; internals bf16, fp32 accumulate.
//
// ws (bf16-el units, 35.65 MB proven-safe):
//   Wb    [0, 4194304)         weights rotate -> M_xs (x-attn OutB)
//   q1q2  [4194304, 12582912)  kvs_b -> Q outputs [4096x2048] -> Wt_xp
//   Mbuf  [12582912, 16777216) kvx_b -> qs_b -> M_s -> qx_b -> M_x
//   kvpx  [16777216,+524288)   Kp [4096x64] + Vt [4][64][1024]
//   kvps  [17301504,+524288)
// d_out lo = bf16 scratch for M_sx (dead before final x_out write).
// All launches sequential on one stream -> aliasing race-free.
//
// attn v5 = v4 (T14 reg-staging + setprio, proven value path) with
// KVBLK 128->64: LDS 51.2->25.5 KB lifts occupancy 3->6 blocks/CU
// (3->6 waves/SIMD). R3 showed the kernel is ~65% idle with all pipes
// cold at 3 waves/SIMD -> TLP-bound; same total LDS traffic, doubled
// chain overlap. Value path unchanged (__expf, f2bf, qscale 0.125).
// ---------------------------------------------------------------------------

typedef short short8 __attribute__((ext_vector_type(8)));
typedef short short4v __attribute__((ext_vector_type(4)));
typedef float floatx4 __attribute__((ext_vector_type(4)));

__device__ __forceinline__ float b2f(ushort h) {
    union { unsigned u; float f; } v; v.u = ((unsigned)h) << 16; return v.f;
}
__device__ __forceinline__ ushort f2bf(float f) {
    union { float f; unsigned u; } v; v.f = f;
    return (ushort)((v.u + 0x7FFFu + ((v.u >> 16) & 1u)) >> 16);
}
__device__ __forceinline__ void gl_lds16(const ushort* g, ushort* l) {
    __builtin_amdgcn_global_load_lds(
        (const __attribute__((address_space(1))) void*)g,
        (__attribute__((address_space(3))) void*)l, 16, 0, 0);
}

// ---------------------------------------------------------------------------
// Batched fp32 -> bf16 cast. grid (4096, 1, nz), block 256: 4 el/thread.
// ---------------------------------------------------------------------------
struct CB { const float* src[2]; ushort* dst[2]; };

__global__ __launch_bounds__(256) void castb(CB cb) {
    const int z = blockIdx.z;
    const float* s = cb.src[z];
    ushort* d = cb.dst[z];
    const size_t i = ((size_t)blockIdx.x * 256 + threadIdx.x) * 4;
    floatx4 f = *(const floatx4*)&s[i];
    short4v o;
#pragma unroll
    for (int k = 0; k < 4; k++) o[k] = (short)f2bf(f[k]);
    *(short4v*)&d[i] = o;
}

// ---------------------------------------------------------------------------
// Batched fp32->bf16 weight transpose: Wt[n*K+k] = bf16(W[k*N+n])
// ---------------------------------------------------------------------------
struct TB { const float* src[4]; ushort* dst[4]; int K[4]; int N[4]; };

__global__ __launch_bounds__(256) void tbatch(TB tb) {
    __shared__ float tile[32][33];
    const int wi = blockIdx.z;
    const int K = tb.K[wi], N = tb.N[wi];
    const int k0 = blockIdx.x * 32, n0 = blockIdx.y * 32;
    if (k0 >= K || n0 >= N) return;
    const float* W = tb.src[wi];
    ushort* Wt = tb.dst[wi];
    const int tx = threadIdx.x & 31, ty = threadIdx.x >> 5;
#pragma unroll
    for (int i = ty; i < 32; i += 8)
        tile[i][tx] = W[(size_t)(k0 + i) * N + n0 + tx];
    __syncthreads();
#pragma unroll
    for (int i = ty; i < 32; i += 8)
        Wt[(size_t)(n0 + i) * K + k0 + tx] = f2bf(tile[tx][i]);
}

// ---------------------------------------------------------------------------
// Q-GEMM (all bf16, fully async staged): C = cscale*(A[4096x1024] @ Bt^T),
// Bt [2048][1024], C bf16 ldc=2048. grid (32, 16), block 256.
// ---------------------------------------------------------------------------
__global__ __launch_bounds__(256) void gemm_q(
    const ushort* __restrict__ A, const ushort* __restrict__ Bt,
    ushort* __restrict__ C, float cscale)
{
    __shared__ ushort As[128 * 32];
    __shared__ ushort Bs[128 * 32];
    const int t = threadIdx.x;
    const int lane = t & 63, w = t >> 6;
    const int q = lane >> 4, li = lane & 15;
    const int wr = (w >> 1) * 64, wc = (w & 1) * 64;
    const int rowA = blockIdx.x * 128, colB = blockIdx.y * 128;
    const int ar = rowA + w * 32 + (lane >> 2);
    const int br = colB + w * 32 + (lane >> 2);
    const int cl = (lane & 3) * 8;
    ushort* adst = &As[w * 32 * 32];
    ushort* bdst = &Bs[w * 32 * 32];

    floatx4 acc[4][4];
    const floatx4 z4 = {0.f, 0.f, 0.f, 0.f};
#pragma unroll
    for (int i = 0; i < 4; i++)
#pragma unroll
        for (int j = 0; j < 4; j++) acc[i][j] = z4;

    for (int k0 = 0; k0 < 1024; k0 += 32) {
        gl_lds16(A + (size_t)ar * 1024 + k0 + cl, adst);
        gl_lds16(A + (size_t)(ar + 16) * 1024 + k0 + cl, adst + 16 * 32);
        gl_lds16(Bt + (size_t)br * 1024 + k0 + cl, bdst);
        gl_lds16(Bt + (size_t)(br + 16) * 1024 + k0 + cl, bdst + 16 * 32);
        __syncthreads();
        short8 af[4], bf[4];
#pragma unroll
        for (int i = 0; i < 4; i++) af[i] = *(const short8*)&As[(wr + i * 16 + li) * 32 + q * 8];
#pragma unroll
        for (int j = 0; j < 4; j++) bf[j] = *(const short8*)&Bs[(wc + j * 16 + li) * 32 + q * 8];
#pragma unroll
        for (int i = 0; i < 4; i++)
#pragma unroll
            for (int j = 0; j < 4; j++)
                acc[i][j] = __builtin_amdgcn_mfma_f32_16x16x32_bf16(af[i], bf[j], acc[i][j], 0, 0, 0);
        __syncthreads();
    }
#pragma unroll
    for (int i = 0; i < 4; i++) {
        const int rowb = rowA + wr + i * 16 + q * 4;
#pragma unroll
        for (int j = 0; j < 4; j++) {
            const int col = colB + wc + j * 16 + li;
#pragma unroll
            for (int r = 0; r < 4; r++)
                C[(size_t)(rowb + r) * 2048 + col] = f2bf(acc[i][j][r] * cscale);
        }
    }
}

// ---------------------------------------------------------------------------
// KV-GEMM (z=2 batched): C = A[4096x1024] @ Bt[128][1024]^T; epilogue splits
// cols 0-63 -> Kp[row*64+col], 64-127 -> Vt[b][d][tok]. grid (32,1,2).
// ---------------------------------------------------------------------------
__global__ __launch_bounds__(256) void gemm_kv(
    const ushort* __restrict__ A0, const ushort* __restrict__ A1,
    const ushort* __restrict__ B0, const ushort* __restrict__ B1,
    ushort* __restrict__ C0, ushort* __restrict__ C1,
    ushort* __restrict__ vt0, ushort* __restrict__ vt1)
{
    __shared__ ushort As[128 * 32];
    __shared__ ushort Bs[128 * 32];
    const int z = blockIdx.z;
    const ushort* A = z ? A1 : A0;
    const ushort* Bt = z ? B1 : B0;
    ushort* Kp = z ? C1 : C0;
    ushort* vt = z ? vt1 : vt0;

    const int t = threadIdx.x;
    const int lane = t & 63, w = t >> 6;
    const int q = lane >> 4, li = lane & 15;
    const int wr = (w >> 1) * 64, wc = (w & 1) * 64;
    const int rowA = blockIdx.x * 128;
    const int ar = rowA + w * 32 + (lane >> 2);
    const int br = w * 32 + (lane >> 2);
    const int cl = (lane & 3) * 8;
    ushort* adst = &As[w * 32 * 32];
    ushort* bdst = &Bs[w * 32 * 32];

    floatx4 acc[4][4];
    const floatx4 z4 = {0.f, 0.f, 0.f, 0.f};
#pragma unroll
    for (int i = 0; i < 4; i++)
#pragma unroll
        for (int j = 0; j < 4; j++) acc[i][j] = z4;

    for (int k0 = 0; k0 < 1024; k0 += 32) {
        gl_lds16(A + (size_t)ar * 1024 + k0 + cl, adst);
        gl_lds16(A + (size_t)(ar + 16) * 1024 + k0 + cl, adst + 16 * 32);
        gl_lds16(Bt + (size_t)br * 1024 + k0 + cl, bdst);
        gl_lds16(Bt + (size_t)(br + 16) * 1024 + k0 + cl, bdst + 16 * 32);
        __syncthreads();
        short8 af[4], bf[4];
#pragma unroll
        for (int i = 0; i < 4; i++) af[i] = *(const short8*)&As[(wr + i * 16 + li) * 32 + q * 8];
#pragma unroll
        for (int j = 0; j < 4; j++) bf[j] = *(const short8*)&Bs[(wc + j * 16 + li) * 32 + q * 8];
#pragma unroll
        for (int i = 0; i < 4; i++)
#pragma unroll
            for (int j = 0; j < 4; j++)
                acc[i][j] = __builtin_amdgcn_mfma_f32_16x16x32_bf16(af[i], bf[j], acc[i][j], 0, 0, 0);
        __syncthreads();
    }
#pragma unroll
    for (int i = 0; i < 4; i++) {
        const int rowb = rowA + wr + i * 16 + q * 4;
#pragma unroll
        for (int j = 0; j < 4; j++) {
            const int col = wc + j * 16 + li;
#pragma unroll
            for (int r = 0; r < 4; r++) {
                const int row = rowb + r;
                const ushort vb = f2bf(acc[i][j][r]);
                if (col < 64) Kp[(size_t)row * 64 + col] = vb;
                else vt[((row >> 10) << 16) + ((col - 64) << 10) + (row & 1023)] = vb;
            }
        }
    }
}

// ---------------------------------------------------------------------------
// Fused concat-projection GEMM, K=2048: C = [A1|A2] @ Bt^T + bias (fp32 out).
// K-remap ks = (kp>>6)*128 + (kp&63) + 64*(k>=1024). grid (32, 8).
// ---------------------------------------------------------------------------
__global__ __launch_bounds__(256) void gemm_proj(
    const ushort* __restrict__ A1, const ushort* __restrict__ A2,
    const ushort* __restrict__ Bt, const float* __restrict__ bias,
    float* __restrict__ C)
{
    __shared__ ushort As[128 * 32];
    __shared__ ushort Bs[128 * 32];
    const int t = threadIdx.x;
    const int lane = t & 63, w = t >> 6;
    const int q = lane >> 4, li = lane & 15;
    const int wr = (w >> 1) * 64, wc = (w & 1) * 64;
    const int rowA = blockIdx.x * 128, colB = blockIdx.y * 128;
    const int ar = rowA + w * 32 + (lane >> 2);
    const int br = colB + w * 32 + (lane >> 2);
    const int cl = (lane & 3) * 8;
    ushort* adst = &As[w * 32 * 32];
    ushort* bdst = &Bs[w * 32 * 32];

    floatx4 acc[4][4];
    const floatx4 z4 = {0.f, 0.f, 0.f, 0.f};
#pragma unroll
    for (int i = 0; i < 4; i++)
#pragma unroll
        for (int j = 0; j < 4; j++) acc[i][j] = z4;

    for (int k0 = 0; k0 < 2048; k0 += 32) {
        const ushort* Ap = (k0 < 1024) ? A1 : A2;
        const int kc = k0 & 1023;
        const int kp = kc + cl;
        const int ks = ((kp >> 6) << 7) + (kp & 63) + ((k0 >= 1024) ? 64 : 0);
        gl_lds16(Ap + (size_t)ar * 1024 + kc + cl, adst);
        gl_lds16(Ap + (size_t)(ar + 16) * 1024 + kc + cl, adst + 16 * 32);
        gl_lds16(Bt + (size_t)br * 2048 + ks, bdst);
        gl_lds16(Bt + (size_t)(br + 16) * 2048 + ks, bdst + 16 * 32);
        __syncthreads();
        short8 af[4], bf[4];
#pragma unroll
        for (int i = 0; i < 4; i++) af[i] = *(const short8*)&As[(wr + i * 16 + li) * 32 + q * 8];
#pragma unroll
        for (int j = 0; j < 4; j++) bf[j] = *(const short8*)&Bs[(wc + j * 16 + li) * 32 + q * 8];
#pragma unroll
        for (int i = 0; i < 4; i++)
#pragma unroll
            for (int j = 0; j < 4; j++)
                acc[i][j] = __builtin_amdgcn_mfma_f32_16x16x32_bf16(af[i], bf[j], acc[i][j], 0, 0, 0);
        __syncthreads();
    }
#pragma unroll
    for (int i = 0; i < 4; i++) {
        const int rowb = rowA + wr + i * 16 + q * 4;
#pragma unroll
        for (int j = 0; j < 4; j++) {
            const int col = colB + wc + j * 16 + li;
            const float bv = bias[col];
#pragma unroll
            for (int r = 0; r < 4; r++)
                C[(size_t)(rowb + r) * 1024 + col] = acc[i][j][r] + bv;
        }
    }
}

// ---------------------------------------------------------------------------
// Flash attention v5: KVBLK=64 tiles (16 iters), LDS 25.5 KB -> 6 blk/CU.
// T14 reg-staging (issue next tile's loads right after the staging barrier),
// wave-private Ps round trip (no barrier), setprio(1) around MFMA clusters.
// grid (16 qtiles, 16 heads, 8 = b*2+a2), block 256.
// ---------------------------------------------------------------------------
__global__ __launch_bounds__(256, 6) void attn_kernel(
    const ushort* __restrict__ Qbase,
    const ushort* __restrict__ KVa, const ushort* __restrict__ KVb,
    ushort* __restrict__ OutA, ushort* __restrict__ OutB)
{
    __shared__ ushort Kt[64 * 68];  // [key][d]    (d stride 64+4)
    __shared__ ushort Vt[64 * 68];  // [d][key]    (key stride 64+4)
    __shared__ ushort Ps[64 * 68];  // [qrow][key] wave-private rows

    const int t = threadIdx.x;
    const int lane = t & 63, w = t >> 6;
    const int q = lane >> 4, li = lane & 15;
    const int qt = blockIdx.x, h = blockIdx.y;
    const int z = blockIdx.z, b = z >> 1, a2 = z & 1;

    const ushort* Q  = Qbase + (a2 ? 1024 : 0);
    const ushort* KV = a2 ? KVb : KVa;
    ushort* Out      = a2 ? OutB : OutA;
    const ushort* Kp = KV;
    const ushort* Vg = KV + 262144;

    const size_t qrow = (size_t)(b * 1024 + qt * 64 + w * 16 + li);
    short8 qf0 = *(const short8*)&Q[qrow * 2048 + h * 64 + q * 8];
    short8 qf1 = *(const short8*)&Q[qrow * 2048 + h * 64 + 32 + q * 8];

    float lsum[4] = {0.f, 0.f, 0.f, 0.f};
    floatx4 O[4];
    const floatx4 z4 = {0.f, 0.f, 0.f, 0.f};
#pragma unroll
    for (int j = 0; j < 4; j++) O[j] = z4;

    // staging map: 64 rows x 64 el, 4 threads/row, 16 el (2 x short8) each
    const int krow = t >> 2, kch = (t & 3) * 16;  // K: [key][d]
    const int vd = t >> 2, vch = (t & 3) * 16;    // V: [d][key]
    const ushort* ksrc0 = &Kp[(size_t)(b * 1024 + krow) * 64 + kch];
    const ushort* vsrc0 = &Vg[(size_t)(b * 64 + vd) * 1024 + vch];
    ushort* kdst = &Kt[krow * 68 + kch];
    ushort* vdst = &Vt[vd * 68 + vch];

    // T14 prologue: tile 0 -> regs
    short8 kreg[2], vreg[2];
#pragma unroll
    for (int i = 0; i < 2; i++) {
        kreg[i] = *(const short8*)&ksrc0[i * 8];
        vreg[i] = *(const short8*)&vsrc0[i * 8];
    }

    for (int kt = 0; kt < 16; kt++) {
        // drain staged regs -> LDS (vmcnt wait inserted by compiler)
#pragma unroll
        for (int i = 0; i < 2; i++) {
            *(short8*)&kdst[i * 8] = kreg[i];
            *(short8*)&vdst[i * 8] = vreg[i];
        }
        __syncthreads();

        // issue NEXT tile's loads now; latency hides under compute below
        if (kt < 15) {
            const ushort* ksrc = ksrc0 + (size_t)(kt + 1) * 64 * 64;
            const ushort* vsrc = vsrc0 + (kt + 1) * 64;
#pragma unroll
            for (int i = 0; i < 2; i++) {
                kreg[i] = *(const short8*)&ksrc[i * 8];
                vreg[i] = *(const short8*)&vsrc[i * 8];
            }
        }

        floatx4 s4[4];
        __builtin_amdgcn_s_setprio(1);
#pragma unroll
        for (int j = 0; j < 4; j++) {
            short8 kf0 = *(const short8*)&Kt[(j * 16 + li) * 68 + q * 8];
            short8 kf1 = *(const short8*)&Kt[(j * 16 + li) * 68 + 32 + q * 8];
            s4[j] = __builtin_amdgcn_mfma_f32_16x16x32_bf16(qf0, kf0, z4, 0, 0, 0);
            s4[j] = __builtin_amdgcn_mfma_f32_16x16x32_bf16(qf1, kf1, s4[j], 0, 0, 0);
        }
        __builtin_amdgcn_s_setprio(0);
#pragma unroll
        for (int j = 0; j < 4; j++)
#pragma unroll
            for (int r = 0; r < 4; r++)
                s4[j][r] = __expf(s4[j][r]);
#pragma unroll
        for (int r = 0; r < 4; r++)
            lsum[r] += (s4[0][r] + s4[1][r]) + (s4[2][r] + s4[3][r]);
#pragma unroll
        for (int j = 0; j < 4; j++)
#pragma unroll
            for (int r = 0; r < 4; r++)
                Ps[(w * 16 + q * 4 + r) * 68 + j * 16 + li] = f2bf(s4[j][r]);
        // no barrier: Ps rows are wave-private; compiler orders via lgkmcnt
        __builtin_amdgcn_s_setprio(1);
#pragma unroll
        for (int kk = 0; kk < 2; kk++) {
            short8 pf = *(const short8*)&Ps[(w * 16 + li) * 68 + kk * 32 + q * 8];
#pragma unroll
            for (int jn = 0; jn < 4; jn++) {
                short8 vf = *(const short8*)&Vt[(jn * 16 + li) * 68 + kk * 32 + q * 8];
                O[jn] = __builtin_amdgcn_mfma_f32_16x16x32_bf16(pf, vf, O[jn], 0, 0, 0);
            }
        }
        __builtin_amdgcn_s_setprio(0);
        __syncthreads();  // retire Kt/Vt readers before next drain
    }

#pragma unroll
    for (int off = 1; off < 16; off <<= 1)
#pragma unroll
        for (int r = 0; r < 4; r++)
            lsum[r] += __shfl_xor(lsum[r], off);

    const int orow = b * 1024 + qt * 64 + w * 16 + q * 4;
#pragma unroll
    for (int r = 0; r < 4; r++) {
        const float inv = 1.f / lsum[r];
#pragma unroll
        for (int j = 0; j < 4; j++)
            Out[(size_t)(orow + r) * 1024 + h * 64 + j * 16 + li] = f2bf(O[j][r] * inv);
    }
}

// ---------------------------------------------------------------------------
extern "C" void kernel_launch(void* const* d_in, const int* in_sizes, int n_in,
                              void* d_out, int out_size, void* d_ws, size_t ws_size,
                              hipStream_t stream) {
    const float* qx    = (const float*)d_in[0];
    const float* kvx   = (const float*)d_in[1];
    const float* qs    = (const float*)d_in[2];
    const float* kvs   = (const float*)d_in[3];
    const float* w_qx1 = (const float*)d_in[4];
    const float* w_qs1 = (const float*)d_in[5];
    const float* w_qx2 = (const float*)d_in[6];
    const float* w_qs2 = (const float*)d_in[7];
    const float* w_kvx = (const float*)d_in[8];
    const float* w_kvs = (const float*)d_in[9];
    const float* w_xp  = (const float*)d_in[10];
    const float* b_xp  = (const float*)d_in[11];
    const float* w_sp  = (const float*)d_in[12];
    const float* b_sp  = (const float*)d_in[13];
    float* out = (float*)d_out;
    (void)ws_size; (void)in_sizes; (void)n_in; (void)out_size;

    ushort* ws   = (ushort*)d_ws;
    ushort* Wb   = ws;
    ushort* q1q2 = ws + 4194304;
    ushort* Mbuf = ws + 12582912;
    ushort* kvpx = ws + 16777216;
    ushort* kvps = ws + 17301504;

    // 1) cast kv activations: kvx_b -> Mbuf, kvs_b -> q1q2 (both dead regions)
    CB c1; c1.src[0] = kvx; c1.dst[0] = Mbuf; c1.src[1] = kvs; c1.dst[1] = q1q2;
    castb<<<dim3(4096, 1, 2), 256, 0, stream>>>(c1);

    // 2) transpose kv + s-path Q weights into Wb
    TB tb1;
    tb1.src[0] = w_kvx; tb1.dst[0] = Wb;           tb1.K[0] = 1024; tb1.N[0] = 128;
    tb1.src[1] = w_kvs; tb1.dst[1] = Wb + 131072;  tb1.K[1] = 1024; tb1.N[1] = 128;
    tb1.src[2] = w_qs1; tb1.dst[2] = Wb + 262144;  tb1.K[2] = 1024; tb1.N[2] = 1024;
    tb1.src[3] = w_qs2; tb1.dst[3] = Wb + 1310720; tb1.K[3] = 1024; tb1.N[3] = 1024;
    tbatch<<<dim3(32, 32, 4), 256, 0, stream>>>(tb1);

    // 3) kv projections (z=2): K->Kp, V->Vt
    gemm_kv<<<dim3(32, 1, 2), 256, 0, stream>>>(
        Mbuf, q1q2, Wb, Wb + 131072, kvpx, kvps, kvpx + 262144, kvps + 262144);

    // 4) cast qs -> Mbuf (kvx_b dead)
    CB c2; c2.src[0] = qs; c2.dst[0] = Mbuf; c2.src[1] = qs; c2.dst[1] = Mbuf;
    castb<<<dim3(4096, 1, 1), 256, 0, stream>>>(c2);

    // 5) s-path Q GEMM: q1s|q2s -> q1q2 (kvs_b dead), scale 1/8 folded
    gemm_q<<<dim3(32, 16), 256, 0, stream>>>(Mbuf, Wb + 262144, q1q2, 0.125f);

    // 6) s attention: M_s -> Mbuf (qs_b dead), M_sx -> d_out lo (bf16 scratch)
    attn_kernel<<<dim3(16, 16, 8), 256, 0, stream>>>(q1q2, kvps, kvpx, Mbuf, (ushort*)out);

    // 7) transpose sp + x-path Q weights (Wt_kv/Wt_qs dead)
    TB tb2;
    tb2.src[0] = w_sp;  tb2.dst[0] = Wb;           tb2.K[0] = 2048; tb2.N[0] = 1024;
    tb2.src[1] = w_qx1; tb2.dst[1] = Wb + 2097152; tb2.K[1] = 1024; tb2.N[1] = 1024;
    tb2.src[2] = w_qx2; tb2.dst[2] = Wb + 3145728; tb2.K[2] = 1024; tb2.N[2] = 1024;
    tb2.src[3] = w_sp;  tb2.dst[3] = Wb;           tb2.K[3] = 0;    tb2.N[3] = 0;
    tbatch<<<dim3(64, 32, 3), 256, 0, stream>>>(tb2);

    // 8) s_out = [M_sx | M_s] @ Wsp^T + b_sp -> d_out hi (fp32)
    gemm_proj<<<dim3(32, 8), 256, 0, stream>>>((ushort*)out, Mbuf, Wb, b_sp, out + 4194304);

    // 9) cast qx -> Mbuf (M_s dead)
    CB c3; c3.src[0] = qx; c3.dst[0] = Mbuf; c3.src[1] = qx; c3.dst[1] = Mbuf;
    castb<<<dim3(4096, 1, 1), 256, 0, stream>>>(c3);

    // 10) x-path Q GEMM -> q1q2 (dead after s-attn)
    gemm_q<<<dim3(32, 16), 256, 0, stream>>>(Mbuf, Wb + 2097152, q1q2, 0.125f);

    // 11) x attention: M_x -> Mbuf (qx_b dead), M_xs -> Wb (weights dead)
    attn_kernel<<<dim3(16, 16, 8), 256, 0, stream>>>(q1q2, kvpx, kvps, Mbuf, Wb);

    // 12) transpose xp -> q1q2 (dead after x-attn)
    TB tb3;
    tb3.src[0] = w_xp; tb3.dst[0] = q1q2; tb3.K[0] = 2048; tb3.N[0] = 1024;
    tb3.src[1] = w_xp; tb3.dst[1] = q1q2; tb3.K[1] = 0;    tb3.N[1] = 0;
    tb3.src[2] = w_xp; tb3.dst[2] = q1q2; tb3.K[2] = 0;    tb3.N[2] = 0;
    tb3.src[3] = w_xp; tb3.dst[3] = q1q2; tb3.K[3] = 0;    tb3.N[3] = 0;
    tbatch<<<dim3(64, 32, 1), 256, 0, stream>>>(tb3);

    // 13) x_out = [M_xs | M_x] @ Wxp^T + b_xp -> d_out lo (M_sx scratch dead)
    gemm_proj<<<dim3(32, 8), 256, 0, stream>>>(Wb, Mbuf, q1q2, b_xp, out);
}

// Round 5
// 451.929 us; speedup vs baseline: 1.7482x; 1.2359x over previous
//
#include <hip/hip_runtime.h>
#include <hip/hip_bf16.h>

// ---------------------------------------------------------------------------
// RecurrentAttention: B=4, L=1024, D_MODEL=1024, N_HEAD=16, D_HEAD=64
// Inputs/outputs fp32; internals bf16, fp32 accumulate.
//
// ws (bf16-el units, 35.65 MB proven-safe):
//   Wb    [0, 4194304)         weights rotate -> M_xs (x-attn OutB)
//   q1q2  [4194304, 12582912)  kvs_b -> Q outputs [4096x2048] -> Wt_xp
//   Mbuf  [12582912, 16777216) kvx_b -> qs_b -> M_s -> qx_b -> M_x
//   kvpx  [16777216,+524288)   Kp [4096x64] + Vt [4][64][1024]
//   kvps  [17301504,+524288)
// d_out lo = bf16 scratch for M_sx (dead before final x_out write).
// All launches sequential on one stream -> aliasing race-free.
//
// attn v6: 32x32 swapped-QK^T in-register softmax (guide SB m214/T12).
// R4 evidence: LDS pipe ~61% busy (K/V/Ps DS ops), all else <25%, and
// occupancy doubling didn't move dur -> cut DS ops per q-row.
//   S^T = mfma_32x32x16(K, Q): lane holds 32 key-scores of ONE q-row
//   -> lsum lane-local, NO Ps round-trip. P -> PV A-frag via
//   16 cvt_pk + 8 permlane32_swap per 64-key tile (exchange derived,
//   matches guide's crow(r,hi) formula). Wave covers 32 q-rows (2x) with
//   same K/V reads -> DS cyc/q-row ~3x down. Block=128 q-rows, grid
//   (8,16,8)=1024 blocks = 4/CU resident. exp stays __expf (compiler
//   handles trans-use hazard; r1's asm v_exp was the corruption).
// ---------------------------------------------------------------------------

typedef short short8 __attribute__((ext_vector_type(8)));
typedef short short4v __attribute__((ext_vector_type(4)));
typedef float floatx4 __attribute__((ext_vector_type(4)));
typedef float floatx16 __attribute__((ext_vector_type(16)));
typedef unsigned uintx2 __attribute__((ext_vector_type(2)));

__device__ __forceinline__ float b2f(ushort h) {
    union { unsigned u; float f; } v; v.u = ((unsigned)h) << 16; return v.f;
}
__device__ __forceinline__ ushort f2bf(float f) {
    union { float f; unsigned u; } v; v.f = f;
    return (ushort)((v.u + 0x7FFFu + ((v.u >> 16) & 1u)) >> 16);
}
__device__ __forceinline__ unsigned cvt_pk_bf16(float lo, float hi) {
    unsigned r;
    asm("v_cvt_pk_bf16_f32 %0, %1, %2" : "=v"(r) : "v"(lo), "v"(hi));
    return r;
}
__device__ __forceinline__ void gl_lds16(const ushort* g, ushort* l) {
    __builtin_amdgcn_global_load_lds(
        (const __attribute__((address_space(1))) void*)g,
        (__attribute__((address_space(3))) void*)l, 16, 0, 0);
}

// ---------------------------------------------------------------------------
// Batched fp32 -> bf16 cast. grid (4096, 1, nz), block 256: 4 el/thread.
// ---------------------------------------------------------------------------
struct CB { const float* src[2]; ushort* dst[2]; };

__global__ __launch_bounds__(256) void castb(CB cb) {
    const int z = blockIdx.z;
    const float* s = cb.src[z];
    ushort* d = cb.dst[z];
    const size_t i = ((size_t)blockIdx.x * 256 + threadIdx.x) * 4;
    floatx4 f = *(const floatx4*)&s[i];
    short4v o;
#pragma unroll
    for (int k = 0; k < 4; k++) o[k] = (short)f2bf(f[k]);
    *(short4v*)&d[i] = o;
}

// ---------------------------------------------------------------------------
// Batched fp32->bf16 weight transpose: Wt[n*K+k] = bf16(W[k*N+n])
// ---------------------------------------------------------------------------
struct TB { const float* src[4]; ushort* dst[4]; int K[4]; int N[4]; };

__global__ __launch_bounds__(256) void tbatch(TB tb) {
    __shared__ float tile[32][33];
    const int wi = blockIdx.z;
    const int K = tb.K[wi], N = tb.N[wi];
    const int k0 = blockIdx.x * 32, n0 = blockIdx.y * 32;
    if (k0 >= K || n0 >= N) return;
    const float* W = tb.src[wi];
    ushort* Wt = tb.dst[wi];
    const int tx = threadIdx.x & 31, ty = threadIdx.x >> 5;
#pragma unroll
    for (int i = ty; i < 32; i += 8)
        tile[i][tx] = W[(size_t)(k0 + i) * N + n0 + tx];
    __syncthreads();
#pragma unroll
    for (int i = ty; i < 32; i += 8)
        Wt[(size_t)(n0 + i) * K + k0 + tx] = f2bf(tile[tx][i]);
}

// ---------------------------------------------------------------------------
// Q-GEMM (all bf16, fully async staged): C = cscale*(A[4096x1024] @ Bt^T),
// Bt [2048][1024], C bf16 ldc=2048. grid (32, 16), block 256.
// ---------------------------------------------------------------------------
__global__ __launch_bounds__(256) void gemm_q(
    const ushort* __restrict__ A, const ushort* __restrict__ Bt,
    ushort* __restrict__ C, float cscale)
{
    __shared__ ushort As[128 * 32];
    __shared__ ushort Bs[128 * 32];
    const int t = threadIdx.x;
    const int lane = t & 63, w = t >> 6;
    const int q = lane >> 4, li = lane & 15;
    const int wr = (w >> 1) * 64, wc = (w & 1) * 64;
    const int rowA = blockIdx.x * 128, colB = blockIdx.y * 128;
    const int ar = rowA + w * 32 + (lane >> 2);
    const int br = colB + w * 32 + (lane >> 2);
    const int cl = (lane & 3) * 8;
    ushort* adst = &As[w * 32 * 32];
    ushort* bdst = &Bs[w * 32 * 32];

    floatx4 acc[4][4];
    const floatx4 z4 = {0.f, 0.f, 0.f, 0.f};
#pragma unroll
    for (int i = 0; i < 4; i++)
#pragma unroll
        for (int j = 0; j < 4; j++) acc[i][j] = z4;

    for (int k0 = 0; k0 < 1024; k0 += 32) {
        gl_lds16(A + (size_t)ar * 1024 + k0 + cl, adst);
        gl_lds16(A + (size_t)(ar + 16) * 1024 + k0 + cl, adst + 16 * 32);
        gl_lds16(Bt + (size_t)br * 1024 + k0 + cl, bdst);
        gl_lds16(Bt + (size_t)(br + 16) * 1024 + k0 + cl, bdst + 16 * 32);
        __syncthreads();
        short8 af[4], bf[4];
#pragma unroll
        for (int i = 0; i < 4; i++) af[i] = *(const short8*)&As[(wr + i * 16 + li) * 32 + q * 8];
#pragma unroll
        for (int j = 0; j < 4; j++) bf[j] = *(const short8*)&Bs[(wc + j * 16 + li) * 32 + q * 8];
#pragma unroll
        for (int i = 0; i < 4; i++)
#pragma unroll
            for (int j = 0; j < 4; j++)
                acc[i][j] = __builtin_amdgcn_mfma_f32_16x16x32_bf16(af[i], bf[j], acc[i][j], 0, 0, 0);
        __syncthreads();
    }
#pragma unroll
    for (int i = 0; i < 4; i++) {
        const int rowb = rowA + wr + i * 16 + q * 4;
#pragma unroll
        for (int j = 0; j < 4; j++) {
            const int col = colB + wc + j * 16 + li;
#pragma unroll
            for (int r = 0; r < 4; r++)
                C[(size_t)(rowb + r) * 2048 + col] = f2bf(acc[i][j][r] * cscale);
        }
    }
}

// ---------------------------------------------------------------------------
// KV-GEMM (z=2 batched): C = A[4096x1024] @ Bt[128][1024]^T; epilogue splits
// cols 0-63 -> Kp[row*64+col], 64-127 -> Vt[b][d][tok]. grid (32,1,2).
// ---------------------------------------------------------------------------
__global__ __launch_bounds__(256) void gemm_kv(
    const ushort* __restrict__ A0, const ushort* __restrict__ A1,
    const ushort* __restrict__ B0, const ushort* __restrict__ B1,
    ushort* __restrict__ C0, ushort* __restrict__ C1,
    ushort* __restrict__ vt0, ushort* __restrict__ vt1)
{
    __shared__ ushort As[128 * 32];
    __shared__ ushort Bs[128 * 32];
    const int z = blockIdx.z;
    const ushort* A = z ? A1 : A0;
    const ushort* Bt = z ? B1 : B0;
    ushort* Kp = z ? C1 : C0;
    ushort* vt = z ? vt1 : vt0;

    const int t = threadIdx.x;
    const int lane = t & 63, w = t >> 6;
    const int q = lane >> 4, li = lane & 15;
    const int wr = (w >> 1) * 64, wc = (w & 1) * 64;
    const int rowA = blockIdx.x * 128;
    const int ar = rowA + w * 32 + (lane >> 2);
    const int br = w * 32 + (lane >> 2);
    const int cl = (lane & 3) * 8;
    ushort* adst = &As[w * 32 * 32];
    ushort* bdst = &Bs[w * 32 * 32];

    floatx4 acc[4][4];
    const floatx4 z4 = {0.f, 0.f, 0.f, 0.f};
#pragma unroll
    for (int i = 0; i < 4; i++)
#pragma unroll
        for (int j = 0; j < 4; j++) acc[i][j] = z4;

    for (int k0 = 0; k0 < 1024; k0 += 32) {
        gl_lds16(A + (size_t)ar * 1024 + k0 + cl, adst);
        gl_lds16(A + (size_t)(ar + 16) * 1024 + k0 + cl, adst + 16 * 32);
        gl_lds16(Bt + (size_t)br * 1024 + k0 + cl, bdst);
        gl_lds16(Bt + (size_t)(br + 16) * 1024 + k0 + cl, bdst + 16 * 32);
        __syncthreads();
        short8 af[4], bf[4];
#pragma unroll
        for (int i = 0; i < 4; i++) af[i] = *(const short8*)&As[(wr + i * 16 + li) * 32 + q * 8];
#pragma unroll
        for (int j = 0; j < 4; j++) bf[j] = *(const short8*)&Bs[(wc + j * 16 + li) * 32 + q * 8];
#pragma unroll
        for (int i = 0; i < 4; i++)
#pragma unroll
            for (int j = 0; j < 4; j++)
                acc[i][j] = __builtin_amdgcn_mfma_f32_16x16x32_bf16(af[i], bf[j], acc[i][j], 0, 0, 0);
        __syncthreads();
    }
#pragma unroll
    for (int i = 0; i < 4; i++) {
        const int rowb = rowA + wr + i * 16 + q * 4;
#pragma unroll
        for (int j = 0; j < 4; j++) {
            const int col = wc + j * 16 + li;
#pragma unroll
            for (int r = 0; r < 4; r++) {
                const int row = rowb + r;
                const ushort vb = f2bf(acc[i][j][r]);
                if (col < 64) Kp[(size_t)row * 64 + col] = vb;
                else vt[((row >> 10) << 16) + ((col - 64) << 10) + (row & 1023)] = vb;
            }
        }
    }
}

// ---------------------------------------------------------------------------
// Fused concat-projection GEMM, K=2048: C = [A1|A2] @ Bt^T + bias (fp32 out).
// K-remap ks = (kp>>6)*128 + (kp&63) + 64*(k>=1024). grid (32, 8).
// ---------------------------------------------------------------------------
__global__ __launch_bounds__(256) void gemm_proj(
    const ushort* __restrict__ A1, const ushort* __restrict__ A2,
    const ushort* __restrict__ Bt, const float* __restrict__ bias,
    float* __restrict__ C)
{
    __shared__ ushort As[128 * 32];
    __shared__ ushort Bs[128 * 32];
    const int t = threadIdx.x;
    const int lane = t & 63, w = t >> 6;
    const int q = lane >> 4, li = lane & 15;
    const int wr = (w >> 1) * 64, wc = (w & 1) * 64;
    const int rowA = blockIdx.x * 128, colB = blockIdx.y * 128;
    const int ar = rowA + w * 32 + (lane >> 2);
    const int br = colB + w * 32 + (lane >> 2);
    const int cl = (lane & 3) * 8;
    ushort* adst = &As[w * 32 * 32];
    ushort* bdst = &Bs[w * 32 * 32];

    floatx4 acc[4][4];
    const floatx4 z4 = {0.f, 0.f, 0.f, 0.f};
#pragma unroll
    for (int i = 0; i < 4; i++)
#pragma unroll
        for (int j = 0; j < 4; j++) acc[i][j] = z4;

    for (int k0 = 0; k0 < 2048; k0 += 32) {
        const ushort* Ap = (k0 < 1024) ? A1 : A2;
        const int kc = k0 & 1023;
        const int kp = kc + cl;
        const int ks = ((kp >> 6) << 7) + (kp & 63) + ((k0 >= 1024) ? 64 : 0);
        gl_lds16(Ap + (size_t)ar * 1024 + kc + cl, adst);
        gl_lds16(Ap + (size_t)(ar + 16) * 1024 + kc + cl, adst + 16 * 32);
        gl_lds16(Bt + (size_t)br * 2048 + ks, bdst);
        gl_lds16(Bt + (size_t)(br + 16) * 2048 + ks, bdst + 16 * 32);
        __syncthreads();
        short8 af[4], bf[4];
#pragma unroll
        for (int i = 0; i < 4; i++) af[i] = *(const short8*)&As[(wr + i * 16 + li) * 32 + q * 8];
#pragma unroll
        for (int j = 0; j < 4; j++) bf[j] = *(const short8*)&Bs[(wc + j * 16 + li) * 32 + q * 8];
#pragma unroll
        for (int i = 0; i < 4; i++)
#pragma unroll
            for (int j = 0; j < 4; j++)
                acc[i][j] = __builtin_amdgcn_mfma_f32_16x16x32_bf16(af[i], bf[j], acc[i][j], 0, 0, 0);
        __syncthreads();
    }
#pragma unroll
    for (int i = 0; i < 4; i++) {
        const int rowb = rowA + wr + i * 16 + q * 4;
#pragma unroll
        for (int j = 0; j < 4; j++) {
            const int col = colB + wc + j * 16 + li;
            const float bv = bias[col];
#pragma unroll
            for (int r = 0; r < 4; r++)
                C[(size_t)(rowb + r) * 1024 + col] = acc[i][j][r] + bv;
        }
    }
}

// ---------------------------------------------------------------------------
// Flash attention v6: 32x32 swapped-QK^T, in-register softmax (no Ps).
// Per wave: 32 q-rows. Per 64-key tile:
//   S^T[ktile] = sum_dc mfma_32x32x16(K[ktile*32+ql][dc*16+hi*8..], Q)
//     -> lane (ql,hi) holds exp-scores of q-row ql, keys (r&3)+8*(r>>2)+4hi+32kt
//   P pack per kslot: 4 cvt_pk + 2 permlane32_swap -> A-frag bf16x8
//   PV: accO[dt] += mfma_32x32x16(pf, V[kslot*16+hi*8..][dt*32+ql])
// lsum lane-local; final lane^32 combine + Ls transpose for normalization.
// K/V LDS-staged (stride 68) with T14 reg-prefetch. grid (8,16,8), 256 thr.
// ---------------------------------------------------------------------------
__global__ __launch_bounds__(256, 4) void attn_kernel(
    const ushort* __restrict__ Qbase,
    const ushort* __restrict__ KVa, const ushort* __restrict__ KVb,
    ushort* __restrict__ OutA, ushort* __restrict__ OutB)
{
    __shared__ ushort Kt[64 * 68];   // [key][d]
    __shared__ ushort Vt[64 * 68];   // [d][key]
    __shared__ __align__(16) float Ls[4][32];  // per-wave lsum transpose

    const int t = threadIdx.x;
    const int lane = t & 63, w = t >> 6;
    const int ql = lane & 31, hi = lane >> 5;
    const int qt = blockIdx.x, h = blockIdx.y;
    const int z = blockIdx.z, b = z >> 1, a2 = z & 1;

    const ushort* Q  = Qbase + (a2 ? 1024 : 0);
    const ushort* KV = a2 ? KVb : KVa;
    ushort* Out      = a2 ? OutB : OutA;
    const ushort* Kp = KV;
    const ushort* Vg = KV + 262144;

    // Q B-fragments (held in regs): B[k=d][n=q] -> lane (ql,hi) holds
    // Q[q=ql][d = dc*16 + hi*8 + 0..7]
    const size_t qrow = (size_t)(b * 1024 + qt * 128 + w * 32 + ql);
    short8 qf[4];
#pragma unroll
    for (int dc = 0; dc < 4; dc++)
        qf[dc] = *(const short8*)&Q[qrow * 2048 + h * 64 + dc * 16 + hi * 8];

    float lsum = 0.f;
    floatx16 accO[2];
#pragma unroll
    for (int dt = 0; dt < 2; dt++)
#pragma unroll
        for (int i = 0; i < 16; i++) accO[dt][i] = 0.f;

    // staging: 64 rows x 64 el, 4 threads/row, 16 el (2 x short8) each
    const int srow = t >> 2, sch = (t & 3) * 16;
    const ushort* ksrc0 = &Kp[(size_t)(b * 1024 + srow) * 64 + sch];
    const ushort* vsrc0 = &Vg[(size_t)(b * 64 + srow) * 1024 + sch];
    ushort* kdst = &Kt[srow * 68 + sch];
    ushort* vdst = &Vt[srow * 68 + sch];

    short8 kreg[2], vreg[2];
#pragma unroll
    for (int i = 0; i < 2; i++) {
        kreg[i] = *(const short8*)&ksrc0[i * 8];
        vreg[i] = *(const short8*)&vsrc0[i * 8];
    }

    for (int kt = 0; kt < 16; kt++) {
        // drain staged regs -> LDS
#pragma unroll
        for (int i = 0; i < 2; i++) {
            *(short8*)&kdst[i * 8] = kreg[i];
            *(short8*)&vdst[i * 8] = vreg[i];
        }
        __syncthreads();

        // T14: issue next tile's loads; latency hides under compute below
        if (kt < 15) {
            const ushort* ksrc = ksrc0 + (size_t)(kt + 1) * 64 * 64;
            const ushort* vsrc = vsrc0 + (kt + 1) * 64;
#pragma unroll
            for (int i = 0; i < 2; i++) {
                kreg[i] = *(const short8*)&ksrc[i * 8];
                vreg[i] = *(const short8*)&vsrc[i * 8];
            }
        }

#pragma unroll
        for (int ktile = 0; ktile < 2; ktile++) {
            // S^T = K-tile (A) x Q (B): lane (ql,hi) gets q-col ql,
            // key rows (r&3) + 8*(r>>2) + 4*hi (+32*ktile)
            floatx16 S;
#pragma unroll
            for (int i = 0; i < 16; i++) S[i] = 0.f;
            __builtin_amdgcn_s_setprio(1);
#pragma unroll
            for (int dc = 0; dc < 4; dc++) {
                short8 kf = *(const short8*)&Kt[(ktile * 32 + ql) * 68 + dc * 16 + hi * 8];
                S = __builtin_amdgcn_mfma_f32_32x32x16_bf16(kf, qf[dc], S, 0, 0, 0);
            }
            __builtin_amdgcn_s_setprio(0);

            float e[16];
#pragma unroll
            for (int r = 0; r < 16; r++) e[r] = __expf(S[r]);
            // lane-local partial row-sum (keys with bit2 == hi)
            float sa = (e[0] + e[1]) + (e[2] + e[3]);
            float sb = (e[4] + e[5]) + (e[6] + e[7]);
            float sc = (e[8] + e[9]) + (e[10] + e[11]);
            float sd = (e[12] + e[13]) + (e[14] + e[15]);
            lsum += (sa + sb) + (sc + sd);

            // P-pack + PV per kslot (kslot = ktile*2 + p)
#pragma unroll
            for (int p = 0; p < 2; p++) {
                // source regs: r = (j&3) + 4*(hi_cons + 2*p)
                unsigned cA = cvt_pk_bf16(e[8 * p + 0], e[8 * p + 1]);  // hi_cons=0, j0,1
                unsigned cC = cvt_pk_bf16(e[8 * p + 2], e[8 * p + 3]);  // hi_cons=0, j2,3
                unsigned cB = cvt_pk_bf16(e[8 * p + 4], e[8 * p + 5]);  // hi_cons=1, j0,1
                unsigned cD = cvt_pk_bf16(e[8 * p + 6], e[8 * p + 7]);  // hi_cons=1, j2,3
                uintx2 s02 = __builtin_amdgcn_permlane32_swap(cA, cB, false, false);
                uintx2 s13 = __builtin_amdgcn_permlane32_swap(cC, cD, false, false);
                union { unsigned u[4]; short8 s; } pf;
                pf.u[0] = s02[0]; pf.u[1] = s13[0];
                pf.u[2] = s02[1]; pf.u[3] = s13[1];
                const int kslot = ktile * 2 + p;
                __builtin_amdgcn_s_setprio(1);
#pragma unroll
                for (int dt = 0; dt < 2; dt++) {
                    short8 vf = *(const short8*)&Vt[(dt * 32 + ql) * 68 + kslot * 16 + hi * 8];
                    accO[dt] = __builtin_amdgcn_mfma_f32_32x32x16_bf16(pf.s, vf, accO[dt], 0, 0, 0);
                }
                __builtin_amdgcn_s_setprio(0);
            }
        }
        __syncthreads();  // retire Kt/Vt readers before next drain
    }

    // full row-sum for q=ql: combine the two key-halves (lane ^ 32)
    lsum += __shfl_xor(lsum, 32);
    Ls[w][ql] = lsum;  // lanes ql and ql+32 write identical value (benign)
    // wave-private: in-wave lgkmcnt ordering suffices, no barrier

    const int orow0 = b * 1024 + qt * 128 + w * 32;
#pragma unroll
    for (int g = 0; g < 4; g++) {
        floatx4 L4 = *(const floatx4*)&Ls[w][g * 8 + hi * 4];
#pragma unroll
        for (int rr = 0; rr < 4; rr++) {
            const float inv = 1.f / L4[rr];
            const int row = orow0 + g * 8 + hi * 4 + rr;
#pragma unroll
            for (int dt = 0; dt < 2; dt++)
                Out[(size_t)row * 1024 + h * 64 + dt * 32 + ql] =
                    f2bf(accO[dt][g * 4 + rr] * inv);
        }
    }
}

// ---------------------------------------------------------------------------
extern "C" void kernel_launch(void* const* d_in, const int* in_sizes, int n_in,
                              void* d_out, int out_size, void* d_ws, size_t ws_size,
                              hipStream_t stream) {
    const float* qx    = (const float*)d_in[0];
    const float* kvx   = (const float*)d_in[1];
    const float* qs    = (const float*)d_in[2];
    const float* kvs   = (const float*)d_in[3];
    const float* w_qx1 = (const float*)d_in[4];
    const float* w_qs1 = (const float*)d_in[5];
    const float* w_qx2 = (const float*)d_in[6];
    const float* w_qs2 = (const float*)d_in[7];
    const float* w_kvx = (const float*)d_in[8];
    const float* w_kvs = (const float*)d_in[9];
    const float* w_xp  = (const float*)d_in[10];
    const float* b_xp  = (const float*)d_in[11];
    const float* w_sp  = (const float*)d_in[12];
    const float* b_sp  = (const float*)d_in[13];
    float* out = (float*)d_out;
    (void)ws_size; (void)in_sizes; (void)n_in; (void)out_size;

    ushort* ws   = (ushort*)d_ws;
    ushort* Wb   = ws;
    ushort* q1q2 = ws + 4194304;
    ushort* Mbuf = ws + 12582912;
    ushort* kvpx = ws + 16777216;
    ushort* kvps = ws + 17301504;

    // 1) cast kv activations: kvx_b -> Mbuf, kvs_b -> q1q2 (both dead regions)
    CB c1; c1.src[0] = kvx; c1.dst[0] = Mbuf; c1.src[1] = kvs; c1.dst[1] = q1q2;
    castb<<<dim3(4096, 1, 2), 256, 0, stream>>>(c1);

    // 2) transpose kv + s-path Q weights into Wb
    TB tb1;
    tb1.src[0] = w_kvx; tb1.dst[0] = Wb;           tb1.K[0] = 1024; tb1.N[0] = 128;
    tb1.src[1] = w_kvs; tb1.dst[1] = Wb + 131072;  tb1.K[1] = 1024; tb1.N[1] = 128;
    tb1.src[2] = w_qs1; tb1.dst[2] = Wb + 262144;  tb1.K[2] = 1024; tb1.N[2] = 1024;
    tb1.src[3] = w_qs2; tb1.dst[3] = Wb + 1310720; tb1.K[3] = 1024; tb1.N[3] = 1024;
    tbatch<<<dim3(32, 32, 4), 256, 0, stream>>>(tb1);

    // 3) kv projections (z=2): K->Kp, V->Vt
    gemm_kv<<<dim3(32, 1, 2), 256, 0, stream>>>(
        Mbuf, q1q2, Wb, Wb + 131072, kvpx, kvps, kvpx + 262144, kvps + 262144);

    // 4) cast qs -> Mbuf (kvx_b dead)
    CB c2; c2.src[0] = qs; c2.dst[0] = Mbuf; c2.src[1] = qs; c2.dst[1] = Mbuf;
    castb<<<dim3(4096, 1, 1), 256, 0, stream>>>(c2);

    // 5) s-path Q GEMM: q1s|q2s -> q1q2 (kvs_b dead), scale 1/8 folded
    gemm_q<<<dim3(32, 16), 256, 0, stream>>>(Mbuf, Wb + 262144, q1q2, 0.125f);

    // 6) s attention: M_s -> Mbuf (qs_b dead), M_sx -> d_out lo (bf16 scratch)
    attn_kernel<<<dim3(8, 16, 8), 256, 0, stream>>>(q1q2, kvps, kvpx, Mbuf, (ushort*)out);

    // 7) transpose sp + x-path Q weights (Wt_kv/Wt_qs dead)
    TB tb2;
    tb2.src[0] = w_sp;  tb2.dst[0] = Wb;           tb2.K[0] = 2048; tb2.N[0] = 1024;
    tb2.src[1] = w_qx1; tb2.dst[1] = Wb + 2097152; tb2.K[1] = 1024; tb2.N[1] = 1024;
    tb2.src[2] = w_qx2; tb2.dst[2] = Wb + 3145728; tb2.K[2] = 1024; tb2.N[2] = 1024;
    tb2.src[3] = w_sp;  tb2.dst[3] = Wb;           tb2.K[3] = 0;    tb2.N[3] = 0;
    tbatch<<<dim3(64, 32, 3), 256, 0, stream>>>(tb2);

    // 8) s_out = [M_sx | M_s] @ Wsp^T + b_sp -> d_out hi (fp32)
    gemm_proj<<<dim3(32, 8), 256, 0, stream>>>((ushort*)out, Mbuf, Wb, b_sp, out + 4194304);

    // 9) cast qx -> Mbuf (M_s dead)
    CB c3; c3.src[0] = qx; c3.dst[0] = Mbuf; c3.src[1] = qx; c3.dst[1] = Mbuf;
    castb<<<dim3(4096, 1, 1), 256, 0, stream>>>(c3);

    // 10) x-path Q GEMM -> q1q2 (dead after s-attn)
    gemm_q<<<dim3(32, 16), 256, 0, stream>>>(Mbuf, Wb + 2097152, q1q2, 0.125f);

    // 11) x attention: M_x -> Mbuf (qx_b dead), M_xs -> Wb (weights dead)
    attn_kernel<<<dim3(8, 16, 8), 256, 0, stream>>>(q1q2, kvpx, kvps, Mbuf, Wb);

    // 12) transpose xp -> q1q2 (dead after x-attn)
    TB tb3;
    tb3.src[0] = w_xp; tb3.dst[0] = q1q2; tb3.K[0] = 2048; tb3.N[0] = 1024;
    tb3.src[1] = w_xp; tb3.dst[1] = q1q2; tb3.K[1] = 0;    tb3.N[1] = 0;
    tb3.src[2] = w_xp; tb3.dst[2] = q1q2; tb3.K[2] = 0;    tb3.N[2] = 0;
    tb3.src[3] = w_xp; tb3.dst[3] = q1q2; tb3.K[3] = 0;    tb3.N[3] = 0;
    tbatch<<<dim3(64, 32, 1), 256, 0, stream>>>(tb3);

    // 13) x_out = [M_xs | M_x] @ Wxp^T + b_xp -> d_out lo (M_sx scratch dead)
    gemm_proj<<<dim3(32, 8), 256, 0, stream>>>(Wb, Mbuf, q1q2, b_xp, out);
}

// Round 7
// 449.082 us; speedup vs baseline: 1.7593x; 1.0063x over previous
//
#include <hip/hip_runtime.h>
#include <hip/hip_bf16.h>

// ---------------------------------------------------------------------------
// RecurrentAttention: B=4, L=1024, D_MODEL=1024, N_HEAD=16, D_HEAD=64
// Inputs/outputs fp32; internals bf16, fp32 accumulate.
//
// ws (bf16-el units, 35.65 MB proven-safe):
//   Wb    [0, 4194304)         weights rotate -> M_xs (x-attn OutB)
//   q1q2  [4194304, 12582912)  kvs_b -> Q outputs [4096x2048] -> Wt_xp
//   Mbuf  [12582912, 16777216) kvx_b -> qs_b -> M_s -> qx_b -> M_x
//   kvpx  [16777216,+524288)   Kp [4096x64] + Vt [4][64][1024]
//   kvps  [17301504,+524288)
// d_out lo = bf16 scratch for M_sx (dead before final x_out write).
// All launches sequential on one stream -> aliasing race-free.
//
// v7 changes (R5 post-mortem: attn 64.6us ea; GEMM pool ~320us dominated by
// co-residency-starved gemm_proj (256 blocks = 1/CU) and gemm_q (2/CU)):
//   - gemm_q / gemm_proj retiled 128x128 -> 128x64: 2x blocks, LDS 12.3 KB,
//     4/CU resp 2/CU co-residency so resident blocks hide the staging
//     barrier drain (m114 mechanism). Fragment math/staging unchanged.
//   - attn: exp -> exp2f builtin (v7.1: __exp2f is a CUDA-ism, doesn't
//     compile on HIP; exp2f lowers to v_exp_f32), log2e folded into
//     gemm_q cscale. attn structure unchanged (v6).
// ---------------------------------------------------------------------------

typedef short short8 __attribute__((ext_vector_type(8)));
typedef short short4v __attribute__((ext_vector_type(4)));
typedef float floatx4 __attribute__((ext_vector_type(4)));
typedef float floatx16 __attribute__((ext_vector_type(16)));
typedef unsigned uintx2 __attribute__((ext_vector_type(2)));

__device__ __forceinline__ float b2f(ushort h) {
    union { unsigned u; float f; } v; v.u = ((unsigned)h) << 16; return v.f;
}
__device__ __forceinline__ ushort f2bf(float f) {
    union { float f; unsigned u; } v; v.f = f;
    return (ushort)((v.u + 0x7FFFu + ((v.u >> 16) & 1u)) >> 16);
}
__device__ __forceinline__ unsigned cvt_pk_bf16(float lo, float hi) {
    unsigned r;
    asm("v_cvt_pk_bf16_f32 %0, %1, %2" : "=v"(r) : "v"(lo), "v"(hi));
    return r;
}
__device__ __forceinline__ void gl_lds16(const ushort* g, ushort* l) {
    __builtin_amdgcn_global_load_lds(
        (const __attribute__((address_space(1))) void*)g,
        (__attribute__((address_space(3))) void*)l, 16, 0, 0);
}

// ---------------------------------------------------------------------------
// Batched fp32 -> bf16 cast. grid (4096, 1, nz), block 256: 4 el/thread.
// ---------------------------------------------------------------------------
struct CB { const float* src[2]; ushort* dst[2]; };

__global__ __launch_bounds__(256) void castb(CB cb) {
    const int z = blockIdx.z;
    const float* s = cb.src[z];
    ushort* d = cb.dst[z];
    const size_t i = ((size_t)blockIdx.x * 256 + threadIdx.x) * 4;
    floatx4 f = *(const floatx4*)&s[i];
    short4v o;
#pragma unroll
    for (int k = 0; k < 4; k++) o[k] = (short)f2bf(f[k]);
    *(short4v*)&d[i] = o;
}

// ---------------------------------------------------------------------------
// Batched fp32->bf16 weight transpose: Wt[n*K+k] = bf16(W[k*N+n])
// ---------------------------------------------------------------------------
struct TB { const float* src[4]; ushort* dst[4]; int K[4]; int N[4]; };

__global__ __launch_bounds__(256) void tbatch(TB tb) {
    __shared__ float tile[32][33];
    const int wi = blockIdx.z;
    const int K = tb.K[wi], N = tb.N[wi];
    const int k0 = blockIdx.x * 32, n0 = blockIdx.y * 32;
    if (k0 >= K || n0 >= N) return;
    const float* W = tb.src[wi];
    ushort* Wt = tb.dst[wi];
    const int tx = threadIdx.x & 31, ty = threadIdx.x >> 5;
#pragma unroll
    for (int i = ty; i < 32; i += 8)
        tile[i][tx] = W[(size_t)(k0 + i) * N + n0 + tx];
    __syncthreads();
#pragma unroll
    for (int i = ty; i < 32; i += 8)
        Wt[(size_t)(n0 + i) * K + k0 + tx] = f2bf(tile[tx][i]);
}

// ---------------------------------------------------------------------------
// Q-GEMM, 128x64 tile (v7): C = cscale*(A[4096x1024] @ Bt^T), Bt [2048][1024],
// C bf16 ldc=2048. grid (32, 32) = 1024 blocks = 4/CU. Per wave: 32 rows x
// 64 cols, acc[2][4]; stage A 2 calls/wave, B 1 call/wave.
// ---------------------------------------------------------------------------
__global__ __launch_bounds__(256) void gemm_q(
    const ushort* __restrict__ A, const ushort* __restrict__ Bt,
    ushort* __restrict__ C, float cscale)
{
    __shared__ ushort As[128 * 32];
    __shared__ ushort Bs[64 * 32];
    const int t = threadIdx.x;
    const int lane = t & 63, w = t >> 6;
    const int q = lane >> 4, li = lane & 15;
    const int rowA = blockIdx.x * 128, colB = blockIdx.y * 64;
    const int ar = rowA + w * 32 + (lane >> 2);
    const int br = colB + w * 16 + (lane >> 2);
    const int cl = (lane & 3) * 8;
    ushort* adst = &As[w * 32 * 32];
    ushort* bdst = &Bs[w * 16 * 32];

    floatx4 acc[2][4];
    const floatx4 z4 = {0.f, 0.f, 0.f, 0.f};
#pragma unroll
    for (int i = 0; i < 2; i++)
#pragma unroll
        for (int j = 0; j < 4; j++) acc[i][j] = z4;

    for (int k0 = 0; k0 < 1024; k0 += 32) {
        gl_lds16(A + (size_t)ar * 1024 + k0 + cl, adst);
        gl_lds16(A + (size_t)(ar + 16) * 1024 + k0 + cl, adst + 16 * 32);
        gl_lds16(Bt + (size_t)br * 1024 + k0 + cl, bdst);
        __syncthreads();
        short8 af[2], bf[4];
#pragma unroll
        for (int i = 0; i < 2; i++) af[i] = *(const short8*)&As[(w * 32 + i * 16 + li) * 32 + q * 8];
#pragma unroll
        for (int j = 0; j < 4; j++) bf[j] = *(const short8*)&Bs[(j * 16 + li) * 32 + q * 8];
#pragma unroll
        for (int i = 0; i < 2; i++)
#pragma unroll
            for (int j = 0; j < 4; j++)
                acc[i][j] = __builtin_amdgcn_mfma_f32_16x16x32_bf16(af[i], bf[j], acc[i][j], 0, 0, 0);
        __syncthreads();
    }
#pragma unroll
    for (int i = 0; i < 2; i++) {
        const int rowb = rowA + w * 32 + i * 16 + q * 4;
#pragma unroll
        for (int j = 0; j < 4; j++) {
            const int col = colB + j * 16 + li;
#pragma unroll
            for (int r = 0; r < 4; r++)
                C[(size_t)(rowb + r) * 2048 + col] = f2bf(acc[i][j][r] * cscale);
        }
    }
}

// ---------------------------------------------------------------------------
// KV-GEMM (z=2 batched): C = A[4096x1024] @ Bt[128][1024]^T; epilogue splits
// cols 0-63 -> Kp[row*64+col], 64-127 -> Vt[b][d][tok]. grid (32,1,2).
// ---------------------------------------------------------------------------
__global__ __launch_bounds__(256) void gemm_kv(
    const ushort* __restrict__ A0, const ushort* __restrict__ A1,
    const ushort* __restrict__ B0, const ushort* __restrict__ B1,
    ushort* __restrict__ C0, ushort* __restrict__ C1,
    ushort* __restrict__ vt0, ushort* __restrict__ vt1)
{
    __shared__ ushort As[128 * 32];
    __shared__ ushort Bs[128 * 32];
    const int z = blockIdx.z;
    const ushort* A = z ? A1 : A0;
    const ushort* Bt = z ? B1 : B0;
    ushort* Kp = z ? C1 : C0;
    ushort* vt = z ? vt1 : vt0;

    const int t = threadIdx.x;
    const int lane = t & 63, w = t >> 6;
    const int q = lane >> 4, li = lane & 15;
    const int wr = (w >> 1) * 64, wc = (w & 1) * 64;
    const int rowA = blockIdx.x * 128;
    const int ar = rowA + w * 32 + (lane >> 2);
    const int br = w * 32 + (lane >> 2);
    const int cl = (lane & 3) * 8;
    ushort* adst = &As[w * 32 * 32];
    ushort* bdst = &Bs[w * 32 * 32];

    floatx4 acc[4][4];
    const floatx4 z4 = {0.f, 0.f, 0.f, 0.f};
#pragma unroll
    for (int i = 0; i < 4; i++)
#pragma unroll
        for (int j = 0; j < 4; j++) acc[i][j] = z4;

    for (int k0 = 0; k0 < 1024; k0 += 32) {
        gl_lds16(A + (size_t)ar * 1024 + k0 + cl, adst);
        gl_lds16(A + (size_t)(ar + 16) * 1024 + k0 + cl, adst + 16 * 32);
        gl_lds16(Bt + (size_t)br * 1024 + k0 + cl, bdst);
        gl_lds16(Bt + (size_t)(br + 16) * 1024 + k0 + cl, bdst + 16 * 32);
        __syncthreads();
        short8 af[4], bf[4];
#pragma unroll
        for (int i = 0; i < 4; i++) af[i] = *(const short8*)&As[(wr + i * 16 + li) * 32 + q * 8];
#pragma unroll
        for (int j = 0; j < 4; j++) bf[j] = *(const short8*)&Bs[(wc + j * 16 + li) * 32 + q * 8];
#pragma unroll
        for (int i = 0; i < 4; i++)
#pragma unroll
            for (int j = 0; j < 4; j++)
                acc[i][j] = __builtin_amdgcn_mfma_f32_16x16x32_bf16(af[i], bf[j], acc[i][j], 0, 0, 0);
        __syncthreads();
    }
#pragma unroll
    for (int i = 0; i < 4; i++) {
        const int rowb = rowA + wr + i * 16 + q * 4;
#pragma unroll
        for (int j = 0; j < 4; j++) {
            const int col = wc + j * 16 + li;
#pragma unroll
            for (int r = 0; r < 4; r++) {
                const int row = rowb + r;
                const ushort vb = f2bf(acc[i][j][r]);
                if (col < 64) Kp[(size_t)row * 64 + col] = vb;
                else vt[((row >> 10) << 16) + ((col - 64) << 10) + (row & 1023)] = vb;
            }
        }
    }
}

// ---------------------------------------------------------------------------
// Fused concat-projection GEMM, 128x64 tile (v7), K=2048:
// C = [A1|A2] @ Bt^T + bias (fp32 out). K-remap ks as before.
// grid (32, 16) = 512 blocks = 2/CU (was 256 = 1/CU).
// ---------------------------------------------------------------------------
__global__ __launch_bounds__(256) void gemm_proj(
    const ushort* __restrict__ A1, const ushort* __restrict__ A2,
    const ushort* __restrict__ Bt, const float* __restrict__ bias,
    float* __restrict__ C)
{
    __shared__ ushort As[128 * 32];
    __shared__ ushort Bs[64 * 32];
    const int t = threadIdx.x;
    const int lane = t & 63, w = t >> 6;
    const int q = lane >> 4, li = lane & 15;
    const int rowA = blockIdx.x * 128, colB = blockIdx.y * 64;
    const int ar = rowA + w * 32 + (lane >> 2);
    const int br = colB + w * 16 + (lane >> 2);
    const int cl = (lane & 3) * 8;
    ushort* adst = &As[w * 32 * 32];
    ushort* bdst = &Bs[w * 16 * 32];

    floatx4 acc[2][4];
    const floatx4 z4 = {0.f, 0.f, 0.f, 0.f};
#pragma unroll
    for (int i = 0; i < 2; i++)
#pragma unroll
        for (int j = 0; j < 4; j++) acc[i][j] = z4;

    for (int k0 = 0; k0 < 2048; k0 += 32) {
        const ushort* Ap = (k0 < 1024) ? A1 : A2;
        const int kc = k0 & 1023;
        const int kp = kc + cl;
        const int ks = ((kp >> 6) << 7) + (kp & 63) + ((k0 >= 1024) ? 64 : 0);
        gl_lds16(Ap + (size_t)ar * 1024 + kc + cl, adst);
        gl_lds16(Ap + (size_t)(ar + 16) * 1024 + kc + cl, adst + 16 * 32);
        gl_lds16(Bt + (size_t)br * 2048 + ks, bdst);
        __syncthreads();
        short8 af[2], bf[4];
#pragma unroll
        for (int i = 0; i < 2; i++) af[i] = *(const short8*)&As[(w * 32 + i * 16 + li) * 32 + q * 8];
#pragma unroll
        for (int j = 0; j < 4; j++) bf[j] = *(const short8*)&Bs[(j * 16 + li) * 32 + q * 8];
#pragma unroll
        for (int i = 0; i < 2; i++)
#pragma unroll
            for (int j = 0; j < 4; j++)
                acc[i][j] = __builtin_amdgcn_mfma_f32_16x16x32_bf16(af[i], bf[j], acc[i][j], 0, 0, 0);
        __syncthreads();
    }
#pragma unroll
    for (int i = 0; i < 2; i++) {
        const int rowb = rowA + w * 32 + i * 16 + q * 4;
#pragma unroll
        for (int j = 0; j < 4; j++) {
            const int col = colB + j * 16 + li;
            const float bv = bias[col];
#pragma unroll
            for (int r = 0; r < 4; r++)
                C[(size_t)(rowb + r) * 1024 + col] = acc[i][j][r] + bv;
        }
    }
}

// ---------------------------------------------------------------------------
// Flash attention v6 (+exp2): 32x32 swapped-QK^T, in-register softmax.
// Q arrives pre-scaled by 0.125*log2e -> exp(x) == exp2f(S) (v_exp_f32).
// grid (8,16,8).
// ---------------------------------------------------------------------------
__global__ __launch_bounds__(256, 4) void attn_kernel(
    const ushort* __restrict__ Qbase,
    const ushort* __restrict__ KVa, const ushort* __restrict__ KVb,
    ushort* __restrict__ OutA, ushort* __restrict__ OutB)
{
    __shared__ ushort Kt[64 * 68];   // [key][d]
    __shared__ ushort Vt[64 * 68];   // [d][key]
    __shared__ __align__(16) float Ls[4][32];  // per-wave lsum transpose

    const int t = threadIdx.x;
    const int lane = t & 63, w = t >> 6;
    const int ql = lane & 31, hi = lane >> 5;
    const int qt = blockIdx.x, h = blockIdx.y;
    const int z = blockIdx.z, b = z >> 1, a2 = z & 1;

    const ushort* Q  = Qbase + (a2 ? 1024 : 0);
    const ushort* KV = a2 ? KVb : KVa;
    ushort* Out      = a2 ? OutB : OutA;
    const ushort* Kp = KV;
    const ushort* Vg = KV + 262144;

    const size_t qrow = (size_t)(b * 1024 + qt * 128 + w * 32 + ql);
    short8 qf[4];
#pragma unroll
    for (int dc = 0; dc < 4; dc++)
        qf[dc] = *(const short8*)&Q[qrow * 2048 + h * 64 + dc * 16 + hi * 8];

    float lsum = 0.f;
    floatx16 accO[2];
#pragma unroll
    for (int dt = 0; dt < 2; dt++)
#pragma unroll
        for (int i = 0; i < 16; i++) accO[dt][i] = 0.f;

    const int srow = t >> 2, sch = (t & 3) * 16;
    const ushort* ksrc0 = &Kp[(size_t)(b * 1024 + srow) * 64 + sch];
    const ushort* vsrc0 = &Vg[(size_t)(b * 64 + srow) * 1024 + sch];
    ushort* kdst = &Kt[srow * 68 + sch];
    ushort* vdst = &Vt[srow * 68 + sch];

    short8 kreg[2], vreg[2];
#pragma unroll
    for (int i = 0; i < 2; i++) {
        kreg[i] = *(const short8*)&ksrc0[i * 8];
        vreg[i] = *(const short8*)&vsrc0[i * 8];
    }

    for (int kt = 0; kt < 16; kt++) {
#pragma unroll
        for (int i = 0; i < 2; i++) {
            *(short8*)&kdst[i * 8] = kreg[i];
            *(short8*)&vdst[i * 8] = vreg[i];
        }
        __syncthreads();

        if (kt < 15) {
            const ushort* ksrc = ksrc0 + (size_t)(kt + 1) * 64 * 64;
            const ushort* vsrc = vsrc0 + (kt + 1) * 64;
#pragma unroll
            for (int i = 0; i < 2; i++) {
                kreg[i] = *(const short8*)&ksrc[i * 8];
                vreg[i] = *(const short8*)&vsrc[i * 8];
            }
        }

#pragma unroll
        for (int ktile = 0; ktile < 2; ktile++) {
            floatx16 S;
#pragma unroll
            for (int i = 0; i < 16; i++) S[i] = 0.f;
            __builtin_amdgcn_s_setprio(1);
#pragma unroll
            for (int dc = 0; dc < 4; dc++) {
                short8 kf = *(const short8*)&Kt[(ktile * 32 + ql) * 68 + dc * 16 + hi * 8];
                S = __builtin_amdgcn_mfma_f32_32x32x16_bf16(kf, qf[dc], S, 0, 0, 0);
            }
            __builtin_amdgcn_s_setprio(0);

            float e[16];
#pragma unroll
            for (int r = 0; r < 16; r++) e[r] = exp2f(S[r]);
            float sa = (e[0] + e[1]) + (e[2] + e[3]);
            float sb = (e[4] + e[5]) + (e[6] + e[7]);
            float sc = (e[8] + e[9]) + (e[10] + e[11]);
            float sd = (e[12] + e[13]) + (e[14] + e[15]);
            lsum += (sa + sb) + (sc + sd);

#pragma unroll
            for (int p = 0; p < 2; p++) {
                unsigned cA = cvt_pk_bf16(e[8 * p + 0], e[8 * p + 1]);
                unsigned cC = cvt_pk_bf16(e[8 * p + 2], e[8 * p + 3]);
                unsigned cB = cvt_pk_bf16(e[8 * p + 4], e[8 * p + 5]);
                unsigned cD = cvt_pk_bf16(e[8 * p + 6], e[8 * p + 7]);
                uintx2 s02 = __builtin_amdgcn_permlane32_swap(cA, cB, false, false);
                uintx2 s13 = __builtin_amdgcn_permlane32_swap(cC, cD, false, false);
                union { unsigned u[4]; short8 s; } pf;
                pf.u[0] = s02[0]; pf.u[1] = s13[0];
                pf.u[2] = s02[1]; pf.u[3] = s13[1];
                const int kslot = ktile * 2 + p;
                __builtin_amdgcn_s_setprio(1);
#pragma unroll
                for (int dt = 0; dt < 2; dt++) {
                    short8 vf = *(const short8*)&Vt[(dt * 32 + ql) * 68 + kslot * 16 + hi * 8];
                    accO[dt] = __builtin_amdgcn_mfma_f32_32x32x16_bf16(pf.s, vf, accO[dt], 0, 0, 0);
                }
                __builtin_amdgcn_s_setprio(0);
            }
        }
        __syncthreads();
    }

    lsum += __shfl_xor(lsum, 32);
    Ls[w][ql] = lsum;

    const int orow0 = b * 1024 + qt * 128 + w * 32;
#pragma unroll
    for (int g = 0; g < 4; g++) {
        floatx4 L4 = *(const floatx4*)&Ls[w][g * 8 + hi * 4];
#pragma unroll
        for (int rr = 0; rr < 4; rr++) {
            const float inv = 1.f / L4[rr];
            const int row = orow0 + g * 8 + hi * 4 + rr;
#pragma unroll
            for (int dt = 0; dt < 2; dt++)
                Out[(size_t)row * 1024 + h * 64 + dt * 32 + ql] =
                    f2bf(accO[dt][g * 4 + rr] * inv);
        }
    }
}

// ---------------------------------------------------------------------------
extern "C" void kernel_launch(void* const* d_in, const int* in_sizes, int n_in,
                              void* d_out, int out_size, void* d_ws, size_t ws_size,
                              hipStream_t stream) {
    const float* qx    = (const float*)d_in[0];
    const float* kvx   = (const float*)d_in[1];
    const float* qs    = (const float*)d_in[2];
    const float* kvs   = (const float*)d_in[3];
    const float* w_qx1 = (const float*)d_in[4];
    const float* w_qs1 = (const float*)d_in[5];
    const float* w_qx2 = (const float*)d_in[6];
    const float* w_qs2 = (const float*)d_in[7];
    const float* w_kvx = (const float*)d_in[8];
    const float* w_kvs = (const float*)d_in[9];
    const float* w_xp  = (const float*)d_in[10];
    const float* b_xp  = (const float*)d_in[11];
    const float* w_sp  = (const float*)d_in[12];
    const float* b_sp  = (const float*)d_in[13];
    float* out = (float*)d_out;
    (void)ws_size; (void)in_sizes; (void)n_in; (void)out_size;

    ushort* ws   = (ushort*)d_ws;
    ushort* Wb   = ws;
    ushort* q1q2 = ws + 4194304;
    ushort* Mbuf = ws + 12582912;
    ushort* kvpx = ws + 16777216;
    ushort* kvps = ws + 17301504;

    // Q scale 1/8 times log2(e): attn uses exp2f directly
    const float qsc = 0.125f * 1.44269504088896f;

    // 1) cast kv activations: kvx_b -> Mbuf, kvs_b -> q1q2 (both dead regions)
    CB c1; c1.src[0] = kvx; c1.dst[0] = Mbuf; c1.src[1] = kvs; c1.dst[1] = q1q2;
    castb<<<dim3(4096, 1, 2), 256, 0, stream>>>(c1);

    // 2) transpose kv + s-path Q weights into Wb
    TB tb1;
    tb1.src[0] = w_kvx; tb1.dst[0] = Wb;           tb1.K[0] = 1024; tb1.N[0] = 128;
    tb1.src[1] = w_kvs; tb1.dst[1] = Wb + 131072;  tb1.K[1] = 1024; tb1.N[1] = 128;
    tb1.src[2] = w_qs1; tb1.dst[2] = Wb + 262144;  tb1.K[2] = 1024; tb1.N[2] = 1024;
    tb1.src[3] = w_qs2; tb1.dst[3] = Wb + 1310720; tb1.K[3] = 1024; tb1.N[3] = 1024;
    tbatch<<<dim3(32, 32, 4), 256, 0, stream>>>(tb1);

    // 3) kv projections (z=2): K->Kp, V->Vt
    gemm_kv<<<dim3(32, 1, 2), 256, 0, stream>>>(
        Mbuf, q1q2, Wb, Wb + 131072, kvpx, kvps, kvpx + 262144, kvps + 262144);

    // 4) cast qs -> Mbuf (kvx_b dead)
    CB c2; c2.src[0] = qs; c2.dst[0] = Mbuf; c2.src[1] = qs; c2.dst[1] = Mbuf;
    castb<<<dim3(4096, 1, 1), 256, 0, stream>>>(c2);

    // 5) s-path Q GEMM: q1s|q2s -> q1q2 (kvs_b dead), scale (1/8)*log2e
    gemm_q<<<dim3(32, 32), 256, 0, stream>>>(Mbuf, Wb + 262144, q1q2, qsc);

    // 6) s attention: M_s -> Mbuf (qs_b dead), M_sx -> d_out lo (bf16 scratch)
    attn_kernel<<<dim3(8, 16, 8), 256, 0, stream>>>(q1q2, kvps, kvpx, Mbuf, (ushort*)out);

    // 7) transpose sp + x-path Q weights (Wt_kv/Wt_qs dead)
    TB tb2;
    tb2.src[0] = w_sp;  tb2.dst[0] = Wb;           tb2.K[0] = 2048; tb2.N[0] = 1024;
    tb2.src[1] = w_qx1; tb2.dst[1] = Wb + 2097152; tb2.K[1] = 1024; tb2.N[1] = 1024;
    tb2.src[2] = w_qx2; tb2.dst[2] = Wb + 3145728; tb2.K[2] = 1024; tb2.N[2] = 1024;
    tb2.src[3] = w_sp;  tb2.dst[3] = Wb;           tb2.K[3] = 0;    tb2.N[3] = 0;
    tbatch<<<dim3(64, 32, 3), 256, 0, stream>>>(tb2);

    // 8) s_out = [M_sx | M_s] @ Wsp^T + b_sp -> d_out hi (fp32)
    gemm_proj<<<dim3(32, 16), 256, 0, stream>>>((ushort*)out, Mbuf, Wb, b_sp, out + 4194304);

    // 9) cast qx -> Mbuf (M_s dead)
    CB c3; c3.src[0] = qx; c3.dst[0] = Mbuf; c3.src[1] = qx; c3.dst[1] = Mbuf;
    castb<<<dim3(4096, 1, 1), 256, 0, stream>>>(c3);

    // 10) x-path Q GEMM -> q1q2 (dead after s-attn)
    gemm_q<<<dim3(32, 32), 256, 0, stream>>>(Mbuf, Wb + 2097152, q1q2, qsc);

    // 11) x attention: M_x -> Mbuf (qx_b dead), M_xs -> Wb (weights dead)
    attn_kernel<<<dim3(8, 16, 8), 256, 0, stream>>>(q1q2, kvpx, kvps, Mbuf, Wb);

    // 12) transpose xp -> q1q2 (dead after x-attn)
    TB tb3;
    tb3.src[0] = w_xp; tb3.dst[0] = q1q2; tb3.K[0] = 2048; tb3.N[0] = 1024;
    tb3.src[1] = w_xp; tb3.dst[1] = q1q2; tb3.K[1] = 0;    tb3.N[1] = 0;
    tb3.src[2] = w_xp; tb3.dst[2] = q1q2; tb3.K[2] = 0;    tb3.N[2] = 0;
    tb3.src[3] = w_xp; tb3.dst[3] = q1q2; tb3.K[3] = 0;    tb3.N[3] = 0;
    tbatch<<<dim3(64, 32, 1), 256, 0, stream>>>(tb3);

    // 13) x_out = [M_xs | M_x] @ Wxp^T + b_xp -> d_out lo (M_sx scratch dead)
    gemm_proj<<<dim3(32, 16), 256, 0, stream>>>(Wb, Mbuf, q1q2, b_xp, out);
}

// Round 8
// 417.484 us; speedup vs baseline: 1.8925x; 1.0757x over previous
//
#include <hip/hip_runtime.h>
#include <hip/hip_bf16.h>

// ---------------------------------------------------------------------------
// RecurrentAttention: B=4, L=1024, D_MODEL=1024, N_HEAD=16, D_HEAD=64
// Inputs/outputs fp32; internals bf16, fp32 accumulate.
//
// ws (bf16-el units, 35.65 MB proven-safe):
//   Wb    [0, 4194304)         weights rotate -> M_xs (x-attn OutB)
//   q1q2  [4194304, 12582912)  kvs_b -> Q outputs [4096x2048] -> Wt_xp
//   Mbuf  [12582912, 16777216) kvx_b -> qs_b -> M_s -> qx_b -> M_x
//   kvpx  [16777216,+524288)   Kp [4096x64] + Vt [4][64][1024]
//   kvps  [17301504,+524288)
// d_out lo = bf16 scratch for M_sx (dead before final x_out write).
// All launches sequential on one stream -> aliasing race-free.
//
// v8 (R7 post-mortem):
//   - exp2f was the PRECISE ocml path (VALUBusy 32->48%, attn +9us) ->
//     revert to __expf + qsc=0.125 (proven 64.6us, round 5).
//   - gemm_q/gemm_proj: BK 32->64 via twin sub-tiles (As0/As1, Bs0/Bs1,
//     each [rows][32] = proven conflict-free stride). Halves barrier pairs
//     per K-loop (16 MFMA/barrier-pair vs 8); LDS 24KB.
// ---------------------------------------------------------------------------

typedef short short8 __attribute__((ext_vector_type(8)));
typedef short short4v __attribute__((ext_vector_type(4)));
typedef float floatx4 __attribute__((ext_vector_type(4)));
typedef float floatx16 __attribute__((ext_vector_type(16)));
typedef unsigned uintx2 __attribute__((ext_vector_type(2)));

__device__ __forceinline__ float b2f(ushort h) {
    union { unsigned u; float f; } v; v.u = ((unsigned)h) << 16; return v.f;
}
__device__ __forceinline__ ushort f2bf(float f) {
    union { float f; unsigned u; } v; v.f = f;
    return (ushort)((v.u + 0x7FFFu + ((v.u >> 16) & 1u)) >> 16);
}
__device__ __forceinline__ unsigned cvt_pk_bf16(float lo, float hi) {
    unsigned r;
    asm("v_cvt_pk_bf16_f32 %0, %1, %2" : "=v"(r) : "v"(lo), "v"(hi));
    return r;
}
__device__ __forceinline__ void gl_lds16(const ushort* g, ushort* l) {
    __builtin_amdgcn_global_load_lds(
        (const __attribute__((address_space(1))) void*)g,
        (__attribute__((address_space(3))) void*)l, 16, 0, 0);
}

// ---------------------------------------------------------------------------
// Batched fp32 -> bf16 cast. grid (4096, 1, nz), block 256: 4 el/thread.
// ---------------------------------------------------------------------------
struct CB { const float* src[2]; ushort* dst[2]; };

__global__ __launch_bounds__(256) void castb(CB cb) {
    const int z = blockIdx.z;
    const float* s = cb.src[z];
    ushort* d = cb.dst[z];
    const size_t i = ((size_t)blockIdx.x * 256 + threadIdx.x) * 4;
    floatx4 f = *(const floatx4*)&s[i];
    short4v o;
#pragma unroll
    for (int k = 0; k < 4; k++) o[k] = (short)f2bf(f[k]);
    *(short4v*)&d[i] = o;
}

// ---------------------------------------------------------------------------
// Batched fp32->bf16 weight transpose: Wt[n*K+k] = bf16(W[k*N+n])
// ---------------------------------------------------------------------------
struct TB { const float* src[4]; ushort* dst[4]; int K[4]; int N[4]; };

__global__ __launch_bounds__(256) void tbatch(TB tb) {
    __shared__ float tile[32][33];
    const int wi = blockIdx.z;
    const int K = tb.K[wi], N = tb.N[wi];
    const int k0 = blockIdx.x * 32, n0 = blockIdx.y * 32;
    if (k0 >= K || n0 >= N) return;
    const float* W = tb.src[wi];
    ushort* Wt = tb.dst[wi];
    const int tx = threadIdx.x & 31, ty = threadIdx.x >> 5;
#pragma unroll
    for (int i = ty; i < 32; i += 8)
        tile[i][tx] = W[(size_t)(k0 + i) * N + n0 + tx];
    __syncthreads();
#pragma unroll
    for (int i = ty; i < 32; i += 8)
        Wt[(size_t)(n0 + i) * K + k0 + tx] = f2bf(tile[tx][i]);
}

// ---------------------------------------------------------------------------
// Q-GEMM, 128x64 tile, BK=64 (v8): C = cscale*(A[4096x1024] @ Bt^T),
// Bt [2048][1024], C bf16 ldc=2048. grid (32, 32) = 1024 blocks = 4/CU.
// Twin K=32 sub-tiles per barrier pair -> 16 MFMA / 2 barriers.
// ---------------------------------------------------------------------------
__global__ __launch_bounds__(256) void gemm_q(
    const ushort* __restrict__ A, const ushort* __restrict__ Bt,
    ushort* __restrict__ C, float cscale)
{
    __shared__ ushort As0[128 * 32];
    __shared__ ushort As1[128 * 32];
    __shared__ ushort Bs0[64 * 32];
    __shared__ ushort Bs1[64 * 32];
    const int t = threadIdx.x;
    const int lane = t & 63, w = t >> 6;
    const int q = lane >> 4, li = lane & 15;
    const int rowA = blockIdx.x * 128, colB = blockIdx.y * 64;
    const int ar = rowA + w * 32 + (lane >> 2);
    const int br = colB + w * 16 + (lane >> 2);
    const int cl = (lane & 3) * 8;
    ushort* adst0 = &As0[w * 32 * 32];
    ushort* adst1 = &As1[w * 32 * 32];
    ushort* bdst0 = &Bs0[w * 16 * 32];
    ushort* bdst1 = &Bs1[w * 16 * 32];

    floatx4 acc[2][4];
    const floatx4 z4 = {0.f, 0.f, 0.f, 0.f};
#pragma unroll
    for (int i = 0; i < 2; i++)
#pragma unroll
        for (int j = 0; j < 4; j++) acc[i][j] = z4;

    for (int k0 = 0; k0 < 1024; k0 += 64) {
        gl_lds16(A + (size_t)ar * 1024 + k0 + cl, adst0);
        gl_lds16(A + (size_t)(ar + 16) * 1024 + k0 + cl, adst0 + 16 * 32);
        gl_lds16(A + (size_t)ar * 1024 + k0 + 32 + cl, adst1);
        gl_lds16(A + (size_t)(ar + 16) * 1024 + k0 + 32 + cl, adst1 + 16 * 32);
        gl_lds16(Bt + (size_t)br * 1024 + k0 + cl, bdst0);
        gl_lds16(Bt + (size_t)br * 1024 + k0 + 32 + cl, bdst1);
        __syncthreads();
        short8 af[2], bf[4];
#pragma unroll
        for (int i = 0; i < 2; i++) af[i] = *(const short8*)&As0[(w * 32 + i * 16 + li) * 32 + q * 8];
#pragma unroll
        for (int j = 0; j < 4; j++) bf[j] = *(const short8*)&Bs0[(j * 16 + li) * 32 + q * 8];
#pragma unroll
        for (int i = 0; i < 2; i++)
#pragma unroll
            for (int j = 0; j < 4; j++)
                acc[i][j] = __builtin_amdgcn_mfma_f32_16x16x32_bf16(af[i], bf[j], acc[i][j], 0, 0, 0);
#pragma unroll
        for (int i = 0; i < 2; i++) af[i] = *(const short8*)&As1[(w * 32 + i * 16 + li) * 32 + q * 8];
#pragma unroll
        for (int j = 0; j < 4; j++) bf[j] = *(const short8*)&Bs1[(j * 16 + li) * 32 + q * 8];
#pragma unroll
        for (int i = 0; i < 2; i++)
#pragma unroll
            for (int j = 0; j < 4; j++)
                acc[i][j] = __builtin_amdgcn_mfma_f32_16x16x32_bf16(af[i], bf[j], acc[i][j], 0, 0, 0);
        __syncthreads();
    }
#pragma unroll
    for (int i = 0; i < 2; i++) {
        const int rowb = rowA + w * 32 + i * 16 + q * 4;
#pragma unroll
        for (int j = 0; j < 4; j++) {
            const int col = colB + j * 16 + li;
#pragma unroll
            for (int r = 0; r < 4; r++)
                C[(size_t)(rowb + r) * 2048 + col] = f2bf(acc[i][j][r] * cscale);
        }
    }
}

// ---------------------------------------------------------------------------
// KV-GEMM (z=2 batched): C = A[4096x1024] @ Bt[128][1024]^T; epilogue splits
// cols 0-63 -> Kp[row*64+col], 64-127 -> Vt[b][d][tok]. grid (32,1,2).
// ---------------------------------------------------------------------------
__global__ __launch_bounds__(256) void gemm_kv(
    const ushort* __restrict__ A0, const ushort* __restrict__ A1,
    const ushort* __restrict__ B0, const ushort* __restrict__ B1,
    ushort* __restrict__ C0, ushort* __restrict__ C1,
    ushort* __restrict__ vt0, ushort* __restrict__ vt1)
{
    __shared__ ushort As[128 * 32];
    __shared__ ushort Bs[128 * 32];
    const int z = blockIdx.z;
    const ushort* A = z ? A1 : A0;
    const ushort* Bt = z ? B1 : B0;
    ushort* Kp = z ? C1 : C0;
    ushort* vt = z ? vt1 : vt0;

    const int t = threadIdx.x;
    const int lane = t & 63, w = t >> 6;
    const int q = lane >> 4, li = lane & 15;
    const int wr = (w >> 1) * 64, wc = (w & 1) * 64;
    const int rowA = blockIdx.x * 128;
    const int ar = rowA + w * 32 + (lane >> 2);
    const int br = w * 32 + (lane >> 2);
    const int cl = (lane & 3) * 8;
    ushort* adst = &As[w * 32 * 32];
    ushort* bdst = &Bs[w * 32 * 32];

    floatx4 acc[4][4];
    const floatx4 z4 = {0.f, 0.f, 0.f, 0.f};
#pragma unroll
    for (int i = 0; i < 4; i++)
#pragma unroll
        for (int j = 0; j < 4; j++) acc[i][j] = z4;

    for (int k0 = 0; k0 < 1024; k0 += 32) {
        gl_lds16(A + (size_t)ar * 1024 + k0 + cl, adst);
        gl_lds16(A + (size_t)(ar + 16) * 1024 + k0 + cl, adst + 16 * 32);
        gl_lds16(Bt + (size_t)br * 1024 + k0 + cl, bdst);
        gl_lds16(Bt + (size_t)(br + 16) * 1024 + k0 + cl, bdst + 16 * 32);
        __syncthreads();
        short8 af[4], bf[4];
#pragma unroll
        for (int i = 0; i < 4; i++) af[i] = *(const short8*)&As[(wr + i * 16 + li) * 32 + q * 8];
#pragma unroll
        for (int j = 0; j < 4; j++) bf[j] = *(const short8*)&Bs[(wc + j * 16 + li) * 32 + q * 8];
#pragma unroll
        for (int i = 0; i < 4; i++)
#pragma unroll
            for (int j = 0; j < 4; j++)
                acc[i][j] = __builtin_amdgcn_mfma_f32_16x16x32_bf16(af[i], bf[j], acc[i][j], 0, 0, 0);
        __syncthreads();
    }
#pragma unroll
    for (int i = 0; i < 4; i++) {
        const int rowb = rowA + wr + i * 16 + q * 4;
#pragma unroll
        for (int j = 0; j < 4; j++) {
            const int col = wc + j * 16 + li;
#pragma unroll
            for (int r = 0; r < 4; r++) {
                const int row = rowb + r;
                const ushort vb = f2bf(acc[i][j][r]);
                if (col < 64) Kp[(size_t)row * 64 + col] = vb;
                else vt[((row >> 10) << 16) + ((col - 64) << 10) + (row & 1023)] = vb;
            }
        }
    }
}

// ---------------------------------------------------------------------------
// Fused concat-projection GEMM, 128x64 tile, BK=64 (v8), K=2048:
// C = [A1|A2] @ Bt^T + bias (fp32 out). grid (32, 16) = 512 blocks = 2/CU.
// ---------------------------------------------------------------------------
__global__ __launch_bounds__(256) void gemm_proj(
    const ushort* __restrict__ A1, const ushort* __restrict__ A2,
    const ushort* __restrict__ Bt, const float* __restrict__ bias,
    float* __restrict__ C)
{
    __shared__ ushort As0[128 * 32];
    __shared__ ushort As1[128 * 32];
    __shared__ ushort Bs0[64 * 32];
    __shared__ ushort Bs1[64 * 32];
    const int t = threadIdx.x;
    const int lane = t & 63, w = t >> 6;
    const int q = lane >> 4, li = lane & 15;
    const int rowA = blockIdx.x * 128, colB = blockIdx.y * 64;
    const int ar = rowA + w * 32 + (lane >> 2);
    const int br = colB + w * 16 + (lane >> 2);
    const int cl = (lane & 3) * 8;
    ushort* adst0 = &As0[w * 32 * 32];
    ushort* adst1 = &As1[w * 32 * 32];
    ushort* bdst0 = &Bs0[w * 16 * 32];
    ushort* bdst1 = &Bs1[w * 16 * 32];

    floatx4 acc[2][4];
    const floatx4 z4 = {0.f, 0.f, 0.f, 0.f};
#pragma unroll
    for (int i = 0; i < 2; i++)
#pragma unroll
        for (int j = 0; j < 4; j++) acc[i][j] = z4;

    for (int k0 = 0; k0 < 2048; k0 += 64) {
        const ushort* Ap = (k0 < 1024) ? A1 : A2;
        const int kc = k0 & 1023;
        const int kp0 = kc + cl;
        const int kp1 = kc + 32 + cl;
        const int koff = (k0 >= 1024) ? 64 : 0;
        const int ks0 = ((kp0 >> 6) << 7) + (kp0 & 63) + koff;
        const int ks1 = ((kp1 >> 6) << 7) + (kp1 & 63) + koff;
        gl_lds16(Ap + (size_t)ar * 1024 + kc + cl, adst0);
        gl_lds16(Ap + (size_t)(ar + 16) * 1024 + kc + cl, adst0 + 16 * 32);
        gl_lds16(Ap + (size_t)ar * 1024 + kc + 32 + cl, adst1);
        gl_lds16(Ap + (size_t)(ar + 16) * 1024 + kc + 32 + cl, adst1 + 16 * 32);
        gl_lds16(Bt + (size_t)br * 2048 + ks0, bdst0);
        gl_lds16(Bt + (size_t)br * 2048 + ks1, bdst1);
        __syncthreads();
        short8 af[2], bf[4];
#pragma unroll
        for (int i = 0; i < 2; i++) af[i] = *(const short8*)&As0[(w * 32 + i * 16 + li) * 32 + q * 8];
#pragma unroll
        for (int j = 0; j < 4; j++) bf[j] = *(const short8*)&Bs0[(j * 16 + li) * 32 + q * 8];
#pragma unroll
        for (int i = 0; i < 2; i++)
#pragma unroll
            for (int j = 0; j < 4; j++)
                acc[i][j] = __builtin_amdgcn_mfma_f32_16x16x32_bf16(af[i], bf[j], acc[i][j], 0, 0, 0);
#pragma unroll
        for (int i = 0; i < 2; i++) af[i] = *(const short8*)&As1[(w * 32 + i * 16 + li) * 32 + q * 8];
#pragma unroll
        for (int j = 0; j < 4; j++) bf[j] = *(const short8*)&Bs1[(j * 16 + li) * 32 + q * 8];
#pragma unroll
        for (int i = 0; i < 2; i++)
#pragma unroll
            for (int j = 0; j < 4; j++)
                acc[i][j] = __builtin_amdgcn_mfma_f32_16x16x32_bf16(af[i], bf[j], acc[i][j], 0, 0, 0);
        __syncthreads();
    }
#pragma unroll
    for (int i = 0; i < 2; i++) {
        const int rowb = rowA + w * 32 + i * 16 + q * 4;
#pragma unroll
        for (int j = 0; j < 4; j++) {
            const int col = colB + j * 16 + li;
            const float bv = bias[col];
#pragma unroll
            for (int r = 0; r < 4; r++)
                C[(size_t)(rowb + r) * 1024 + col] = acc[i][j][r] + bv;
        }
    }
}

// ---------------------------------------------------------------------------
// Flash attention v6 (round-5 proven config): 32x32 swapped-QK^T,
// in-register softmax, __expf value path, qscale 0.125. grid (8,16,8).
// ---------------------------------------------------------------------------
__global__ __launch_bounds__(256, 4) void attn_kernel(
    const ushort* __restrict__ Qbase,
    const ushort* __restrict__ KVa, const ushort* __restrict__ KVb,
    ushort* __restrict__ OutA, ushort* __restrict__ OutB)
{
    __shared__ ushort Kt[64 * 68];   // [key][d]
    __shared__ ushort Vt[64 * 68];   // [d][key]
    __shared__ __align__(16) float Ls[4][32];  // per-wave lsum transpose

    const int t = threadIdx.x;
    const int lane = t & 63, w = t >> 6;
    const int ql = lane & 31, hi = lane >> 5;
    const int qt = blockIdx.x, h = blockIdx.y;
    const int z = blockIdx.z, b = z >> 1, a2 = z & 1;

    const ushort* Q  = Qbase + (a2 ? 1024 : 0);
    const ushort* KV = a2 ? KVb : KVa;
    ushort* Out      = a2 ? OutB : OutA;
    const ushort* Kp = KV;
    const ushort* Vg = KV + 262144;

    const size_t qrow = (size_t)(b * 1024 + qt * 128 + w * 32 + ql);
    short8 qf[4];
#pragma unroll
    for (int dc = 0; dc < 4; dc++)
        qf[dc] = *(const short8*)&Q[qrow * 2048 + h * 64 + dc * 16 + hi * 8];

    float lsum = 0.f;
    floatx16 accO[2];
#pragma unroll
    for (int dt = 0; dt < 2; dt++)
#pragma unroll
        for (int i = 0; i < 16; i++) accO[dt][i] = 0.f;

    const int srow = t >> 2, sch = (t & 3) * 16;
    const ushort* ksrc0 = &Kp[(size_t)(b * 1024 + srow) * 64 + sch];
    const ushort* vsrc0 = &Vg[(size_t)(b * 64 + srow) * 1024 + sch];
    ushort* kdst = &Kt[srow * 68 + sch];
    ushort* vdst = &Vt[srow * 68 + sch];

    short8 kreg[2], vreg[2];
#pragma unroll
    for (int i = 0; i < 2; i++) {
        kreg[i] = *(const short8*)&ksrc0[i * 8];
        vreg[i] = *(const short8*)&vsrc0[i * 8];
    }

    for (int kt = 0; kt < 16; kt++) {
#pragma unroll
        for (int i = 0; i < 2; i++) {
            *(short8*)&kdst[i * 8] = kreg[i];
            *(short8*)&vdst[i * 8] = vreg[i];
        }
        __syncthreads();

        if (kt < 15) {
            const ushort* ksrc = ksrc0 + (size_t)(kt + 1) * 64 * 64;
            const ushort* vsrc = vsrc0 + (kt + 1) * 64;
#pragma unroll
            for (int i = 0; i < 2; i++) {
                kreg[i] = *(const short8*)&ksrc[i * 8];
                vreg[i] = *(const short8*)&vsrc[i * 8];
            }
        }

#pragma unroll
        for (int ktile = 0; ktile < 2; ktile++) {
            floatx16 S;
#pragma unroll
            for (int i = 0; i < 16; i++) S[i] = 0.f;
            __builtin_amdgcn_s_setprio(1);
#pragma unroll
            for (int dc = 0; dc < 4; dc++) {
                short8 kf = *(const short8*)&Kt[(ktile * 32 + ql) * 68 + dc * 16 + hi * 8];
                S = __builtin_amdgcn_mfma_f32_32x32x16_bf16(kf, qf[dc], S, 0, 0, 0);
            }
            __builtin_amdgcn_s_setprio(0);

            float e[16];
#pragma unroll
            for (int r = 0; r < 16; r++) e[r] = __expf(S[r]);
            float sa = (e[0] + e[1]) + (e[2] + e[3]);
            float sb = (e[4] + e[5]) + (e[6] + e[7]);
            float sc = (e[8] + e[9]) + (e[10] + e[11]);
            float sd = (e[12] + e[13]) + (e[14] + e[15]);
            lsum += (sa + sb) + (sc + sd);

#pragma unroll
            for (int p = 0; p < 2; p++) {
                unsigned cA = cvt_pk_bf16(e[8 * p + 0], e[8 * p + 1]);
                unsigned cC = cvt_pk_bf16(e[8 * p + 2], e[8 * p + 3]);
                unsigned cB = cvt_pk_bf16(e[8 * p + 4], e[8 * p + 5]);
                unsigned cD = cvt_pk_bf16(e[8 * p + 6], e[8 * p + 7]);
                uintx2 s02 = __builtin_amdgcn_permlane32_swap(cA, cB, false, false);
                uintx2 s13 = __builtin_amdgcn_permlane32_swap(cC, cD, false, false);
                union { unsigned u[4]; short8 s; } pf;
                pf.u[0] = s02[0]; pf.u[1] = s13[0];
                pf.u[2] = s02[1]; pf.u[3] = s13[1];
                const int kslot = ktile * 2 + p;
                __builtin_amdgcn_s_setprio(1);
#pragma unroll
                for (int dt = 0; dt < 2; dt++) {
                    short8 vf = *(const short8*)&Vt[(dt * 32 + ql) * 68 + kslot * 16 + hi * 8];
                    accO[dt] = __builtin_amdgcn_mfma_f32_32x32x16_bf16(pf.s, vf, accO[dt], 0, 0, 0);
                }
                __builtin_amdgcn_s_setprio(0);
            }
        }
        __syncthreads();
    }

    lsum += __shfl_xor(lsum, 32);
    Ls[w][ql] = lsum;

    const int orow0 = b * 1024 + qt * 128 + w * 32;
#pragma unroll
    for (int g = 0; g < 4; g++) {
        floatx4 L4 = *(const floatx4*)&Ls[w][g * 8 + hi * 4];
#pragma unroll
        for (int rr = 0; rr < 4; rr++) {
            const float inv = 1.f / L4[rr];
            const int row = orow0 + g * 8 + hi * 4 + rr;
#pragma unroll
            for (int dt = 0; dt < 2; dt++)
                Out[(size_t)row * 1024 + h * 64 + dt * 32 + ql] =
                    f2bf(accO[dt][g * 4 + rr] * inv);
        }
    }
}

// ---------------------------------------------------------------------------
extern "C" void kernel_launch(void* const* d_in, const int* in_sizes, int n_in,
                              void* d_out, int out_size, void* d_ws, size_t ws_size,
                              hipStream_t stream) {
    const float* qx    = (const float*)d_in[0];
    const float* kvx   = (const float*)d_in[1];
    const float* qs    = (const float*)d_in[2];
    const float* kvs   = (const float*)d_in[3];
    const float* w_qx1 = (const float*)d_in[4];
    const float* w_qs1 = (const float*)d_in[5];
    const float* w_qx2 = (const float*)d_in[6];
    const float* w_qs2 = (const float*)d_in[7];
    const float* w_kvx = (const float*)d_in[8];
    const float* w_kvs = (const float*)d_in[9];
    const float* w_xp  = (const float*)d_in[10];
    const float* b_xp  = (const float*)d_in[11];
    const float* w_sp  = (const float*)d_in[12];
    const float* b_sp  = (const float*)d_in[13];
    float* out = (float*)d_out;
    (void)ws_size; (void)in_sizes; (void)n_in; (void)out_size;

    ushort* ws   = (ushort*)d_ws;
    ushort* Wb   = ws;
    ushort* q1q2 = ws + 4194304;
    ushort* Mbuf = ws + 12582912;
    ushort* kvpx = ws + 16777216;
    ushort* kvps = ws + 17301504;

    // 1) cast kv activations: kvx_b -> Mbuf, kvs_b -> q1q2 (both dead regions)
    CB c1; c1.src[0] = kvx; c1.dst[0] = Mbuf; c1.src[1] = kvs; c1.dst[1] = q1q2;
    castb<<<dim3(4096, 1, 2), 256, 0, stream>>>(c1);

    // 2) transpose kv + s-path Q weights into Wb
    TB tb1;
    tb1.src[0] = w_kvx; tb1.dst[0] = Wb;           tb1.K[0] = 1024; tb1.N[0] = 128;
    tb1.src[1] = w_kvs; tb1.dst[1] = Wb + 131072;  tb1.K[1] = 1024; tb1.N[1] = 128;
    tb1.src[2] = w_qs1; tb1.dst[2] = Wb + 262144;  tb1.K[2] = 1024; tb1.N[2] = 1024;
    tb1.src[3] = w_qs2; tb1.dst[3] = Wb + 1310720; tb1.K[3] = 1024; tb1.N[3] = 1024;
    tbatch<<<dim3(32, 32, 4), 256, 0, stream>>>(tb1);

    // 3) kv projections (z=2): K->Kp, V->Vt
    gemm_kv<<<dim3(32, 1, 2), 256, 0, stream>>>(
        Mbuf, q1q2, Wb, Wb + 131072, kvpx, kvps, kvpx + 262144, kvps + 262144);

    // 4) cast qs -> Mbuf (kvx_b dead)
    CB c2; c2.src[0] = qs; c2.dst[0] = Mbuf; c2.src[1] = qs; c2.dst[1] = Mbuf;
    castb<<<dim3(4096, 1, 1), 256, 0, stream>>>(c2);

    // 5) s-path Q GEMM: q1s|q2s -> q1q2 (kvs_b dead), scale 1/8 folded
    gemm_q<<<dim3(32, 32), 256, 0, stream>>>(Mbuf, Wb + 262144, q1q2, 0.125f);

    // 6) s attention: M_s -> Mbuf (qs_b dead), M_sx -> d_out lo (bf16 scratch)
    attn_kernel<<<dim3(8, 16, 8), 256, 0, stream>>>(q1q2, kvps, kvpx, Mbuf, (ushort*)out);

    // 7) transpose sp + x-path Q weights (Wt_kv/Wt_qs dead)
    TB tb2;
    tb2.src[0] = w_sp;  tb2.dst[0] = Wb;           tb2.K[0] = 2048; tb2.N[0] = 1024;
    tb2.src[1] = w_qx1; tb2.dst[1] = Wb + 2097152; tb2.K[1] = 1024; tb2.N[1] = 1024;
    tb2.src[2] = w_qx2; tb2.dst[2] = Wb + 3145728; tb2.K[2] = 1024; tb2.N[2] = 1024;
    tb2.src[3] = w_sp;  tb2.dst[3] = Wb;           tb2.K[3] = 0;    tb2.N[3] = 0;
    tbatch<<<dim3(64, 32, 3), 256, 0, stream>>>(tb2);

    // 8) s_out = [M_sx | M_s] @ Wsp^T + b_sp -> d_out hi (fp32)
    gemm_proj<<<dim3(32, 16), 256, 0, stream>>>((ushort*)out, Mbuf, Wb, b_sp, out + 4194304);

    // 9) cast qx -> Mbuf (M_s dead)
    CB c3; c3.src[0] = qx; c3.dst[0] = Mbuf; c3.src[1] = qx; c3.dst[1] = Mbuf;
    castb<<<dim3(4096, 1, 1), 256, 0, stream>>>(c3);

    // 10) x-path Q GEMM -> q1q2 (dead after s-attn)
    gemm_q<<<dim3(32, 32), 256, 0, stream>>>(Mbuf, Wb + 2097152, q1q2, 0.125f);

    // 11) x attention: M_x -> Mbuf (qx_b dead), M_xs -> Wb (weights dead)
    attn_kernel<<<dim3(8, 16, 8), 256, 0, stream>>>(q1q2, kvpx, kvps, Mbuf, Wb);

    // 12) transpose xp -> q1q2 (dead after x-attn)
    TB tb3;
    tb3.src[0] = w_xp; tb3.dst[0] = q1q2; tb3.K[0] = 2048; tb3.N[0] = 1024;
    tb3.src[1] = w_xp; tb3.dst[1] = q1q2; tb3.K[1] = 0;    tb3.N[1] = 0;
    tb3.src[2] = w_xp; tb3.dst[2] = q1q2; tb3.K[2] = 0;    tb3.N[2] = 0;
    tb3.src[3] = w_xp; tb3.dst[3] = q1q2; tb3.K[3] = 0;    tb3.N[3] = 0;
    tbatch<<<dim3(64, 32, 1), 256, 0, stream>>>(tb3);

    // 13) x_out = [M_xs | M_x] @ Wxp^T + b_xp -> d_out lo (M_sx scratch dead)
    gemm_proj<<<dim3(32, 16), 256, 0, stream>>>(Wb, Mbuf, q1q2, b_xp, out);
}